// Round 3
// baseline (13191.275 us; speedup 1.0000x reference)
//
#include <hip/hip_runtime.h>
#include <math.h>

#define TPB 256
#define NB 256  // stats blocks per channel

// ---------------- weight binarize: sign(w) -> int8 ----------------
__global__ void k_binw(const float* __restrict__ w, signed char* __restrict__ wb, int n) {
    int i = blockIdx.x * TPB + threadIdx.x;
    if (i < n) {
        float v = w[i];
        wb[i] = v > 0.f ? 1 : (v < 0.f ? -1 : 0);
    }
}

// ---------------- per-channel partial sum / sumsq (double, deterministic) ----------------
template <typename T>
__global__ void k_stats(const T* __restrict__ x, int N, int C, int HW,
                        double* __restrict__ partial /* [C][NB][2] */) {
    int c = blockIdx.y;
    long long total = (long long)N * HW;
    double s1 = 0.0, s2 = 0.0;
    long long stride = (long long)NB * TPB;
    for (long long i = (long long)blockIdx.x * TPB + threadIdx.x; i < total; i += stride) {
        int n = (int)(i / HW);
        int pos = (int)(i - (long long)n * HW);
        double v = (double)x[((long long)n * C + c) * HW + pos];
        s1 += v;
        s2 += v * v;
    }
    for (int off = 32; off > 0; off >>= 1) {
        s1 += __shfl_down(s1, off);
        s2 += __shfl_down(s2, off);
    }
    __shared__ double sh1[TPB / 64], sh2[TPB / 64];
    int wv = threadIdx.x >> 6;
    if ((threadIdx.x & 63) == 0) { sh1[wv] = s1; sh2[wv] = s2; }
    __syncthreads();
    if (threadIdx.x == 0) {
        double t1 = 0.0, t2 = 0.0;
        for (int i = 0; i < TPB / 64; ++i) { t1 += sh1[i]; t2 += sh2[i]; }
        partial[((long long)c * NB + blockIdx.x) * 2 + 0] = t1;
        partial[((long long)c * NB + blockIdx.x) * 2 + 1] = t2;
    }
}

// ---------------- finalize: mean, rstd per channel ----------------
__global__ void k_finalize(const double* __restrict__ partial, double* __restrict__ mr,
                           int C, double cnt) {
    int c = blockIdx.x * blockDim.x + threadIdx.x;
    if (c >= C) return;
    double s1 = 0.0, s2 = 0.0;
    for (int b = 0; b < NB; ++b) {
        s1 += partial[((long long)c * NB + b) * 2 + 0];
        s2 += partial[((long long)c * NB + b) * 2 + 1];
    }
    double mean = s1 / cnt;
    double var = s2 / cnt - mean * mean;
    double rstd = 1.0 / sqrt(var + 1e-5);
    mr[2 * c + 0] = mean;
    mr[2 * c + 1] = rstd;
}

// ---------------- sign(bn(x)) -> int8 ----------------
template <typename T>
__global__ void k_bnsign(const T* __restrict__ x, const double* __restrict__ mr,
                         const float* __restrict__ g, const float* __restrict__ b,
                         signed char* __restrict__ out, int C, int HW, long long total) {
    long long i = (long long)blockIdx.x * TPB + threadIdx.x;
    if (i >= total) return;
    int c = (int)((i / HW) % C);
    double xn = ((double)x[i] - mr[2 * c]) * mr[2 * c + 1];
    double v = xn * (double)g[c] + (double)b[c];
    out[i] = v > 0.0 ? 1 : (v < 0.0 ? -1 : 0);
}

// ---------------- direct conv: int8 x int8 -> int16, stride 1, VALID ----------------
__global__ void k_conv(const signed char* __restrict__ a, const signed char* __restrict__ w,
                       short* __restrict__ out, int N, int CI, int HI, int WI,
                       int CO, int HO, int WO, int KH, int KW) {
    long long total = (long long)N * CO * HO * WO;
    long long idx = (long long)blockIdx.x * TPB + threadIdx.x;
    if (idx >= total) return;
    int ow = (int)(idx % WO);
    long long t = idx / WO;
    int oh = (int)(t % HO); t /= HO;
    int co = (int)(t % CO);
    int n = (int)(t / CO);
    int acc = 0;
    const signed char* wp = w + (long long)co * CI * KH * KW;
    for (int ci = 0; ci < CI; ++ci) {
        const signed char* ap = a + (((long long)n * CI + ci) * HI + oh) * WI + ow;
        for (int kh = 0; kh < KH; ++kh) {
            for (int kw = 0; kw < KW; ++kw)
                acc += (int)ap[kw] * (int)wp[kw];
            ap += WI;
            wp += KW;
        }
    }
    out[idx] = (short)acc;
}

// ---------------- 3x3 maxpool, VALID, stride s ----------------
__global__ void k_pool(const short* __restrict__ in, short* __restrict__ out,
                       int NC, int HI, int WI, int HO, int WO, int s) {
    long long total = (long long)NC * HO * WO;
    long long idx = (long long)blockIdx.x * TPB + threadIdx.x;
    if (idx >= total) return;
    int ow = (int)(idx % WO);
    long long t = idx / WO;
    int oh = (int)(t % HO);
    int nc = (int)(t / HO);
    const short* p = in + ((long long)nc * HI + (long long)oh * s) * WI + (long long)ow * s;
    int m = -1000000;
    for (int kh = 0; kh < 3; ++kh) {
        m = max(m, (int)p[0]);
        m = max(m, (int)p[1]);
        m = max(m, (int)p[2]);
        p += WI;
    }
    out[idx] = (short)m;
}

// ---------------- FC: [64,256] int8 @ [50,256]^T int8 -> float ----------------
__global__ void k_fc(const signed char* __restrict__ a, const signed char* __restrict__ w,
                     float* __restrict__ out) {
    int i = blockIdx.x * TPB + threadIdx.x;
    if (i >= 64 * 50) return;
    int n = i / 50, c = i % 50;
    int acc = 0;
    for (int k = 0; k < 256; ++k)
        acc += (int)a[n * 256 + k] * (int)w[c * 256 + k];
    out[i] = (float)acc;
}

static inline long long cdiv(long long a, long long b) { return (a + b - 1) / b; }

extern "C" void kernel_launch(void* const* d_in, const int* in_sizes, int n_in,
                              void* d_out, int out_size, void* d_ws, size_t ws_size,
                              hipStream_t stream) {
    const float* x = (const float*)d_in[0];
    const float* gs[7] = {(const float*)d_in[1], (const float*)d_in[4], (const float*)d_in[7],
                          (const float*)d_in[10], (const float*)d_in[13], (const float*)d_in[16],
                          (const float*)d_in[19]};
    const float* bs[7] = {(const float*)d_in[2], (const float*)d_in[5], (const float*)d_in[8],
                          (const float*)d_in[11], (const float*)d_in[14], (const float*)d_in[17],
                          (const float*)d_in[20]};
    const float* wsrc[7] = {(const float*)d_in[3], (const float*)d_in[6], (const float*)d_in[9],
                            (const float*)d_in[12], (const float*)d_in[15], (const float*)d_in[18],
                            (const float*)d_in[21]};
    const int wcnt[7] = {8 * 3 * 11 * 11, 16 * 8 * 7 * 7, 32 * 16 * 5 * 5, 32 * 32 * 5 * 5,
                         64 * 32 * 5 * 5, 64 * 64 * 3 * 3, 50 * 256};

    // ---- workspace layout (~84 MB total) ----
    char* ws = (char*)d_ws;
    double* partial = (double*)ws;                          // 64*256*2*8 = 256 KB
    double* mr = (double*)(ws + 262144);                    // 7*128 doubles
    signed char* wb = (signed char*)(ws + 278528);          // 148,440 B binarized weights
    signed char* A = (signed char*)(ws + (1ll << 20));      // int8 activations, 24 MB slot
    short* Cb = (short*)(ws + (25ll << 20));                // conv chunk out int16, 12 MB slot
    short* Pb = (short*)(ws + (37ll << 20));                // pool out int16, 47 MB slot

    // binarize all weights
    long long woff[7];
    {
        long long o = 0;
        for (int i = 0; i < 7; ++i) { woff[i] = o; o += wcnt[i]; }
        for (int i = 0; i < 7; ++i)
            k_binw<<<dim3(cdiv(wcnt[i], TPB)), dim3(TPB), 0, stream>>>(wsrc[i], wb + woff[i], wcnt[i]);
    }

    // layer geometry
    const int C_[7] = {3, 8, 16, 32, 32, 64, 64};       // bn channels (input of layer L)
    const int Hin[7] = {224, 212, 102, 48, 21, 8, 2};   // spatial of bn input
    const int CO_[6] = {8, 16, 32, 32, 64, 64};
    const int K_[6] = {11, 7, 5, 5, 5, 3};
    const int PS_[6] = {1, 2, 2, 2, 2, 2};              // pool strides
    const int NCH_[6] = {16, 8, 16, 64, 64, 64};        // batch chunk for conv/pool scratch
    const int N = 64;

    const short* curP = nullptr;  // bn input for layers 2..7 (int16)

    for (int L = 0; L < 7; ++L) {
        int C = C_[L], H = Hin[L], W = Hin[L];
        int HW = H * W;
        long long nhw = (long long)N * HW;
        long long tot = nhw * C;
        double* mrl = mr + L * 128;
        dim3 sg(NB, C);

        if (L == 0) {
            k_stats<float><<<sg, TPB, 0, stream>>>(x, N, C, HW, partial);
            k_finalize<<<1, 64, 0, stream>>>(partial, mrl, C, (double)nhw);
            k_bnsign<float><<<dim3(cdiv(tot, TPB)), TPB, 0, stream>>>(x, mrl, gs[L], bs[L], A, C, HW, tot);
        } else {
            k_stats<short><<<sg, TPB, 0, stream>>>(curP, N, C, HW, partial);
            k_finalize<<<1, 64, 0, stream>>>(partial, mrl, C, (double)nhw);
            k_bnsign<short><<<dim3(cdiv(tot, TPB)), TPB, 0, stream>>>(curP, mrl, gs[L], bs[L], A, C, HW, tot);
        }

        if (L == 6) {
            k_fc<<<dim3(cdiv(64 * 50, TPB)), TPB, 0, stream>>>(A, wb + woff[6], (float*)d_out);
            break;
        }

        int CO = CO_[L], K = K_[L];
        int HOc = H - K + 1, WOc = W - K + 1;
        int s = PS_[L];
        int HOp = (HOc - 3) / s + 1, WOp = (WOc - 3) / s + 1;
        int nch = NCH_[L];

        for (int n0 = 0; n0 < N; n0 += nch) {
            const signed char* ain = A + (long long)n0 * C * H * W;
            long long ctot = (long long)nch * CO * HOc * WOc;
            k_conv<<<dim3(cdiv(ctot, TPB)), TPB, 0, stream>>>(ain, wb + woff[L], Cb,
                                                              nch, C, H, W, CO, HOc, WOc, K, K);
            long long ptot = (long long)nch * CO * HOp * WOp;
            short* pout = Pb + (long long)n0 * CO * HOp * WOp;
            k_pool<<<dim3(cdiv(ptot, TPB)), TPB, 0, stream>>>(Cb, pout, nch * CO, HOc, WOc, HOp, WOp, s);
        }
        curP = Pb;
    }
}

// Round 4
// 2934.215 us; speedup vs baseline: 4.4957x; 4.4957x over previous
//
#include <hip/hip_runtime.h>
#include <math.h>

#define TPB 256
#define NB 256  // stats blocks per channel

#if __has_builtin(__builtin_amdgcn_sdot4)
#define HAS_SDOT4 1
#else
#define HAS_SDOT4 0
#endif
#if __has_builtin(__builtin_amdgcn_alignbyte)
#define HAS_ALIGN 1
#else
#define HAS_ALIGN 0
#endif

__device__ __forceinline__ int dot4(unsigned int a, unsigned int b, int c) {
#if HAS_SDOT4
    return __builtin_amdgcn_sdot4((int)a, (int)b, c, false);
#else
    c += (int)(signed char)(a) * (int)(signed char)(b);
    c += (int)(signed char)(a >> 8) * (int)(signed char)(b >> 8);
    c += (int)(signed char)(a >> 16) * (int)(signed char)(b >> 16);
    c += (int)(signed char)(a >> 24) * (int)(signed char)(b >> 24);
    return c;
#endif
}

__device__ __forceinline__ unsigned int alignb(unsigned int hi, unsigned int lo, int s) {
#if HAS_ALIGN
    return (unsigned int)__builtin_amdgcn_alignbyte(hi, lo, s);
#else
    return (unsigned int)((((unsigned long long)hi << 32) | (unsigned long long)lo) >> (8 * s));
#endif
}

// ---------------- weight binarize: sign(w) -> int8 ----------------
__global__ void k_binw(const float* __restrict__ w, signed char* __restrict__ wb, int n) {
    int i = blockIdx.x * TPB + threadIdx.x;
    if (i < n) {
        float v = w[i];
        wb[i] = v > 0.f ? 1 : (v < 0.f ? -1 : 0);
    }
}

// ---------------- per-channel partial sum / sumsq (double, deterministic) ----------------
template <typename T>
__global__ void k_stats(const T* __restrict__ x, int N, int C, int HW,
                        double* __restrict__ partial /* [C][NB][2] */) {
    int c = blockIdx.y;
    long long total = (long long)N * HW;
    double s1 = 0.0, s2 = 0.0;
    long long stride = (long long)NB * TPB;
    for (long long i = (long long)blockIdx.x * TPB + threadIdx.x; i < total; i += stride) {
        int n = (int)(i / HW);
        int pos = (int)(i - (long long)n * HW);
        double v = (double)x[((long long)n * C + c) * HW + pos];
        s1 += v;
        s2 += v * v;
    }
    for (int off = 32; off > 0; off >>= 1) {
        s1 += __shfl_down(s1, off);
        s2 += __shfl_down(s2, off);
    }
    __shared__ double sh1[TPB / 64], sh2[TPB / 64];
    int wv = threadIdx.x >> 6;
    if ((threadIdx.x & 63) == 0) { sh1[wv] = s1; sh2[wv] = s2; }
    __syncthreads();
    if (threadIdx.x == 0) {
        double t1 = 0.0, t2 = 0.0;
        for (int i = 0; i < TPB / 64; ++i) { t1 += sh1[i]; t2 += sh2[i]; }
        partial[((long long)c * NB + blockIdx.x) * 2 + 0] = t1;
        partial[((long long)c * NB + blockIdx.x) * 2 + 1] = t2;
    }
}

// ---------------- finalize: mean, rstd per channel ----------------
__global__ void k_finalize(const double* __restrict__ partial, double* __restrict__ mr,
                           int C, double cnt) {
    int c = blockIdx.x * blockDim.x + threadIdx.x;
    if (c >= C) return;
    double s1 = 0.0, s2 = 0.0;
    for (int b = 0; b < NB; ++b) {
        s1 += partial[((long long)c * NB + b) * 2 + 0];
        s2 += partial[((long long)c * NB + b) * 2 + 1];
    }
    double mean = s1 / cnt;
    double var = s2 / cnt - mean * mean;
    double rstd = 1.0 / sqrt(var + 1e-5);
    mr[2 * c + 0] = mean;
    mr[2 * c + 1] = rstd;
}

// ---------------- sign(bn(x)) -> int8 ----------------
template <typename T>
__global__ void k_bnsign(const T* __restrict__ x, const double* __restrict__ mr,
                         const float* __restrict__ g, const float* __restrict__ b,
                         signed char* __restrict__ out, int C, int HW, long long total) {
    long long i = (long long)blockIdx.x * TPB + threadIdx.x;
    if (i >= total) return;
    int c = (int)((i / HW) % C);
    double xn = ((double)x[i] - mr[2 * c]) * mr[2 * c + 1];
    double v = xn * (double)g[c] + (double)b[c];
    out[i] = v > 0.0 ? 1 : (v < 0.0 ? -1 : 0);
}

// ---------------- tiled conv: int8 x int8 -> int16, stride 1, VALID ----------------
// Block: 256 thr; tx=tid&15 -> 4 consecutive ow each (BW=64), ty=tid>>4 -> 16 rows (BH=16).
// Input tile + weight tile (COT output channels, rows padded to Kp) in LDS.
// Inner: 4-wide unaligned windows via v_alignbyte, 4 MACs per v_dot4_i32_i8.
template <int K, int COT>
__global__ __launch_bounds__(256) void k_convt(
    const signed char* __restrict__ a,   // [nch][CI][H][W]
    const signed char* __restrict__ w,   // [CO][CI][K][K]
    short* __restrict__ out,             // [nch][CO][HO][WO]
    int CI, int H, int W, int CO, int HO, int WO) {
    constexpr int Kp = (K + 3) & ~3;
    constexpr int NC = Kp / 4;
    constexpr int R = NC + 1;
    constexpr int BW = 64, BH = 16;
    constexpr int TH = BH + K - 1;
    constexpr int TWt = BW + Kp + 4;
    extern __shared__ unsigned char lds[];
    unsigned char* in_t = lds;                      // CI*TH*TWt
    unsigned char* w_t = lds + CI * TH * TWt;       // COT*CI*K*Kp

    const int n = blockIdx.z;
    const int ow0 = blockIdx.x * BW;
    const int oh0 = blockIdx.y * BH;
    const int tid = threadIdx.x;
    const int tx = tid & 15, ty = tid >> 4;

    // ---- stage input tile (zero-fill out of bounds) ----
    const int tile_elems = CI * TH * TWt;
    for (int t = tid; t < tile_elems; t += TPB) {
        int x = t % TWt;
        int rest = t / TWt;
        int y = rest % TH;
        int ci = rest / TH;
        int gx = ow0 + x, gy = oh0 + y;
        signed char v = 0;
        if (gx < W && gy < H)
            v = a[((long long)(n * CI + ci) * H + gy) * W + gx];
        in_t[t] = (unsigned char)v;
    }

    const int ow = ow0 + tx * 4;
    const int oh = oh0 + ty;

    for (int co0 = 0; co0 < CO; co0 += COT) {
        __syncthreads();  // previous phase done reading w_t / first phase: input staged
        // ---- stage weights [COT][CI][K][Kp], kw>=K zero-padded ----
        const int welems = COT * CI * K * Kp;
        for (int t = tid; t < welems; t += TPB) {
            int kwp = t % Kp;
            int rest = t / Kp;
            int kh = rest % K;
            rest /= K;
            int ci = rest % CI;
            int co = rest / CI;
            signed char v = 0;
            if (kwp < K)
                v = w[(((long long)(co0 + co) * CI + ci) * K + kh) * K + kwp];
            w_t[t] = (unsigned char)v;
        }
        __syncthreads();

        int acc[COT][4];
#pragma unroll
        for (int co = 0; co < COT; ++co)
#pragma unroll
            for (int j = 0; j < 4; ++j) acc[co][j] = 0;

        for (int ci = 0; ci < CI; ++ci) {
#pragma unroll 1
            for (int kh = 0; kh < K; ++kh) {
                const unsigned int* ip =
                    (const unsigned int*)&in_t[(ci * TH + ty + kh) * TWt + tx * 4];
                unsigned int r[R];
#pragma unroll
                for (int i = 0; i < R; ++i) r[i] = ip[i];
                // hoisted unaligned windows, shared across all COT channels
                unsigned int av[NC][4];
#pragma unroll
                for (int c = 0; c < NC; ++c) {
                    av[c][0] = r[c];
                    av[c][1] = alignb(r[c + 1], r[c], 1);
                    av[c][2] = alignb(r[c + 1], r[c], 2);
                    av[c][3] = alignb(r[c + 1], r[c], 3);
                }
                const unsigned char* wrow = &w_t[(ci * K + kh) * Kp];
#pragma unroll
                for (int co = 0; co < COT; ++co) {
                    const unsigned int* wp =
                        (const unsigned int*)(wrow + (size_t)co * CI * K * Kp);
#pragma unroll
                    for (int c = 0; c < NC; ++c) {
                        unsigned int wq = wp[c];
                        acc[co][0] = dot4(av[c][0], wq, acc[co][0]);
                        acc[co][1] = dot4(av[c][1], wq, acc[co][1]);
                        acc[co][2] = dot4(av[c][2], wq, acc[co][2]);
                        acc[co][3] = dot4(av[c][3], wq, acc[co][3]);
                    }
                }
            }
        }

        if (oh < HO && ow < WO) {
#pragma unroll
            for (int co = 0; co < COT; ++co) {
                long long base = ((long long)(n * CO + co0 + co) * HO + oh) * WO;
                if (ow + 3 < WO) {
                    unsigned int p0 = ((unsigned)acc[co][0] & 0xffffu) | ((unsigned)acc[co][1] << 16);
                    unsigned int p1 = ((unsigned)acc[co][2] & 0xffffu) | ((unsigned)acc[co][3] << 16);
                    unsigned int* dst = (unsigned int*)&out[base + ow];
                    dst[0] = p0;
                    dst[1] = p1;
                } else {
                    for (int j = 0; j < 4 && ow + j < WO; ++j)
                        out[base + ow + j] = (short)acc[co][j];
                }
            }
        }
    }
}

// ---------------- simple direct conv (kept for tiny last layer) ----------------
__global__ void k_conv(const signed char* __restrict__ a, const signed char* __restrict__ w,
                       short* __restrict__ out, int N, int CI, int HI, int WI,
                       int CO, int HO, int WO, int KH, int KW) {
    long long total = (long long)N * CO * HO * WO;
    long long idx = (long long)blockIdx.x * TPB + threadIdx.x;
    if (idx >= total) return;
    int ow = (int)(idx % WO);
    long long t = idx / WO;
    int oh = (int)(t % HO); t /= HO;
    int co = (int)(t % CO);
    int n = (int)(t / CO);
    int acc = 0;
    const signed char* wp = w + (long long)co * CI * KH * KW;
    for (int ci = 0; ci < CI; ++ci) {
        const signed char* ap = a + (((long long)n * CI + ci) * HI + oh) * WI + ow;
        for (int kh = 0; kh < KH; ++kh) {
            for (int kw = 0; kw < KW; ++kw)
                acc += (int)ap[kw] * (int)wp[kw];
            ap += WI;
            wp += KW;
        }
    }
    out[idx] = (short)acc;
}

// ---------------- 3x3 maxpool, VALID, stride s ----------------
__global__ void k_pool(const short* __restrict__ in, short* __restrict__ out,
                       int NC, int HI, int WI, int HO, int WO, int s) {
    long long total = (long long)NC * HO * WO;
    long long idx = (long long)blockIdx.x * TPB + threadIdx.x;
    if (idx >= total) return;
    int ow = (int)(idx % WO);
    long long t = idx / WO;
    int oh = (int)(t % HO);
    int nc = (int)(t / HO);
    const short* p = in + ((long long)nc * HI + (long long)oh * s) * WI + (long long)ow * s;
    int m = -1000000;
    for (int kh = 0; kh < 3; ++kh) {
        m = max(m, (int)p[0]);
        m = max(m, (int)p[1]);
        m = max(m, (int)p[2]);
        p += WI;
    }
    out[idx] = (short)m;
}

// ---------------- FC: [64,256] int8 @ [50,256]^T int8 -> float ----------------
__global__ void k_fc(const signed char* __restrict__ a, const signed char* __restrict__ w,
                     float* __restrict__ out) {
    int i = blockIdx.x * TPB + threadIdx.x;
    if (i >= 64 * 50) return;
    int n = i / 50, c = i % 50;
    int acc = 0;
    for (int k = 0; k < 256; ++k)
        acc += (int)a[n * 256 + k] * (int)w[c * 256 + k];
    out[i] = (float)acc;
}

static inline long long cdiv(long long a, long long b) { return (a + b - 1) / b; }

extern "C" void kernel_launch(void* const* d_in, const int* in_sizes, int n_in,
                              void* d_out, int out_size, void* d_ws, size_t ws_size,
                              hipStream_t stream) {
    const float* x = (const float*)d_in[0];
    const float* gs[7] = {(const float*)d_in[1], (const float*)d_in[4], (const float*)d_in[7],
                          (const float*)d_in[10], (const float*)d_in[13], (const float*)d_in[16],
                          (const float*)d_in[19]};
    const float* bs[7] = {(const float*)d_in[2], (const float*)d_in[5], (const float*)d_in[8],
                          (const float*)d_in[11], (const float*)d_in[14], (const float*)d_in[17],
                          (const float*)d_in[20]};
    const float* wsrc[7] = {(const float*)d_in[3], (const float*)d_in[6], (const float*)d_in[9],
                            (const float*)d_in[12], (const float*)d_in[15], (const float*)d_in[18],
                            (const float*)d_in[21]};
    const int wcnt[7] = {8 * 3 * 11 * 11, 16 * 8 * 7 * 7, 32 * 16 * 5 * 5, 32 * 32 * 5 * 5,
                         64 * 32 * 5 * 5, 64 * 64 * 3 * 3, 50 * 256};

    // ---- workspace layout (~84 MB total, identical to passing round) ----
    char* ws = (char*)d_ws;
    double* partial = (double*)ws;                          // 256 KB
    double* mr = (double*)(ws + 262144);                    // 7*128 doubles
    signed char* wb = (signed char*)(ws + 278528);          // binarized weights
    signed char* A = (signed char*)(ws + (1ll << 20));      // int8 activations, 24 MB slot
    short* Cb = (short*)(ws + (25ll << 20));                // conv chunk out int16, 12 MB slot
    short* Pb = (short*)(ws + (37ll << 20));                // pool out int16, 47 MB slot

    // binarize all weights
    long long woff[7];
    {
        long long o = 0;
        for (int i = 0; i < 7; ++i) { woff[i] = o; o += wcnt[i]; }
        for (int i = 0; i < 7; ++i)
            k_binw<<<dim3(cdiv(wcnt[i], TPB)), dim3(TPB), 0, stream>>>(wsrc[i], wb + woff[i], wcnt[i]);
    }

    // layer geometry
    const int C_[7] = {3, 8, 16, 32, 32, 64, 64};       // bn channels (input of layer L)
    const int Hin[7] = {224, 212, 102, 48, 21, 8, 2};   // spatial of bn input
    const int CO_[6] = {8, 16, 32, 32, 64, 64};
    const int K_[6] = {11, 7, 5, 5, 5, 3};
    const int PS_[6] = {1, 2, 2, 2, 2, 2};              // pool strides
    const int NCH_[6] = {16, 8, 16, 64, 64, 64};        // batch chunk for conv/pool scratch
    const int N = 64;

    const short* curP = nullptr;

    for (int L = 0; L < 7; ++L) {
        int C = C_[L], H = Hin[L], W = Hin[L];
        int HW = H * W;
        long long nhw = (long long)N * HW;
        long long tot = nhw * C;
        double* mrl = mr + L * 128;
        dim3 sg(NB, C);

        if (L == 0) {
            k_stats<float><<<sg, TPB, 0, stream>>>(x, N, C, HW, partial);
            k_finalize<<<1, 64, 0, stream>>>(partial, mrl, C, (double)nhw);
            k_bnsign<float><<<dim3(cdiv(tot, TPB)), TPB, 0, stream>>>(x, mrl, gs[L], bs[L], A, C, HW, tot);
        } else {
            k_stats<short><<<sg, TPB, 0, stream>>>(curP, N, C, HW, partial);
            k_finalize<<<1, 64, 0, stream>>>(partial, mrl, C, (double)nhw);
            k_bnsign<short><<<dim3(cdiv(tot, TPB)), TPB, 0, stream>>>(curP, mrl, gs[L], bs[L], A, C, HW, tot);
        }

        if (L == 6) {
            k_fc<<<dim3(cdiv(64 * 50, TPB)), TPB, 0, stream>>>(A, wb + woff[6], (float*)d_out);
            break;
        }

        int CO = CO_[L], K = K_[L];
        int HOc = H - K + 1, WOc = W - K + 1;
        int s = PS_[L];
        int HOp = (HOc - 3) / s + 1, WOp = (WOc - 3) / s + 1;
        int nch = NCH_[L];

        for (int n0 = 0; n0 < N; n0 += nch) {
            const signed char* ain = A + (long long)n0 * C * H * W;
            dim3 cg((unsigned)cdiv(WOc, 64), (unsigned)cdiv(HOc, 16), nch);
            // dynamic LDS: CI*TH*TWt + COT*CI*K*Kp  (all <= 59 KB)
            if (L == 0) {
                size_t lds = (size_t)C * 26 * 80 + (size_t)8 * C * 11 * 12;
                k_convt<11, 8><<<cg, TPB, lds, stream>>>(ain, wb + woff[L], Cb, C, H, W, CO, HOc, WOc);
            } else if (L == 1) {
                size_t lds = (size_t)C * 22 * 76 + (size_t)16 * C * 7 * 8;
                k_convt<7, 16><<<cg, TPB, lds, stream>>>(ain, wb + woff[L], Cb, C, H, W, CO, HOc, WOc);
            } else if (L == 2) {
                size_t lds = (size_t)C * 20 * 76 + (size_t)16 * C * 5 * 8;
                k_convt<5, 16><<<cg, TPB, lds, stream>>>(ain, wb + woff[L], Cb, C, H, W, CO, HOc, WOc);
            } else if (L == 3 || L == 4) {
                size_t lds = (size_t)C * 20 * 76 + (size_t)8 * C * 5 * 8;
                k_convt<5, 8><<<cg, TPB, lds, stream>>>(ain, wb + woff[L], Cb, C, H, W, CO, HOc, WOc);
            } else {
                long long ctot = (long long)nch * CO * HOc * WOc;
                k_conv<<<dim3(cdiv(ctot, TPB)), TPB, 0, stream>>>(ain, wb + woff[L], Cb,
                                                                  nch, C, H, W, CO, HOc, WOc, K, K);
            }
            long long ptot = (long long)nch * CO * HOp * WOp;
            short* pout = Pb + (long long)n0 * CO * HOp * WOp;
            k_pool<<<dim3(cdiv(ptot, TPB)), TPB, 0, stream>>>(Cb, pout, nch * CO, HOc, WOc, HOp, WOp, s);
        }
        curP = Pb;
    }
}

// Round 5
// 1996.205 us; speedup vs baseline: 6.6082x; 1.4699x over previous
//
#include <hip/hip_runtime.h>
#include <math.h>

#define TPB 256
#define NB 256  // stats blocks per channel

#if __has_builtin(__builtin_amdgcn_sdot4)
#define HAS_SDOT4 1
#else
#define HAS_SDOT4 0
#endif
#if __has_builtin(__builtin_amdgcn_alignbyte)
#define HAS_ALIGN 1
#else
#define HAS_ALIGN 0
#endif

__device__ __forceinline__ int dot4(unsigned int a, unsigned int b, int c) {
#if HAS_SDOT4
    return __builtin_amdgcn_sdot4((int)a, (int)b, c, false);
#else
    c += (int)(signed char)(a) * (int)(signed char)(b);
    c += (int)(signed char)(a >> 8) * (int)(signed char)(b >> 8);
    c += (int)(signed char)(a >> 16) * (int)(signed char)(b >> 16);
    c += (int)(signed char)(a >> 24) * (int)(signed char)(b >> 24);
    return c;
#endif
}

__device__ __forceinline__ unsigned int alignb(unsigned int hi, unsigned int lo, int s) {
#if HAS_ALIGN
    return (unsigned int)__builtin_amdgcn_alignbyte(hi, lo, s);
#else
    return (unsigned int)((((unsigned long long)hi << 32) | (unsigned long long)lo) >> (8 * s));
#endif
}

// ---------------- weight binarize (plain, for FC): sign(w) -> int8 ----------------
__global__ void k_binw(const float* __restrict__ w, signed char* __restrict__ wb, int n) {
    int i = blockIdx.x * TPB + threadIdx.x;
    if (i < n) {
        float v = w[i];
        wb[i] = v > 0.f ? 1 : (v < 0.f ? -1 : 0);
    }
}

// ---------------- weight binarize + pad rows to Kp: [CO][CI][K][K] -> [CO][CI][K][Kp] ----------------
__global__ void k_binwpad(const float* __restrict__ w, signed char* __restrict__ wb,
                          int CI, int K, int Kp, int total) {
    int i = blockIdx.x * TPB + threadIdx.x;
    if (i >= total) return;
    int kwp = i % Kp;
    int rest = i / Kp;          // (co*CI+ci)*K + kh
    signed char v = 0;
    if (kwp < K) {
        float f = w[rest * K + kwp];
        v = f > 0.f ? 1 : (f < 0.f ? -1 : 0);
    }
    wb[i] = v;
}

// ---------------- per-channel partial sum / sumsq (double, deterministic) ----------------
template <typename T>
__global__ void k_stats(const T* __restrict__ x, int N, int C, int HW,
                        double* __restrict__ partial /* [C][NB][2] */) {
    int c = blockIdx.y;
    long long total = (long long)N * HW;
    double s1 = 0.0, s2 = 0.0;
    long long stride = (long long)NB * TPB;
    for (long long i = (long long)blockIdx.x * TPB + threadIdx.x; i < total; i += stride) {
        int n = (int)(i / HW);
        int pos = (int)(i - (long long)n * HW);
        double v = (double)x[((long long)n * C + c) * HW + pos];
        s1 += v;
        s2 += v * v;
    }
    for (int off = 32; off > 0; off >>= 1) {
        s1 += __shfl_down(s1, off);
        s2 += __shfl_down(s2, off);
    }
    __shared__ double sh1[TPB / 64], sh2[TPB / 64];
    int wv = threadIdx.x >> 6;
    if ((threadIdx.x & 63) == 0) { sh1[wv] = s1; sh2[wv] = s2; }
    __syncthreads();
    if (threadIdx.x == 0) {
        double t1 = 0.0, t2 = 0.0;
        for (int i = 0; i < TPB / 64; ++i) { t1 += sh1[i]; t2 += sh2[i]; }
        partial[((long long)c * NB + blockIdx.x) * 2 + 0] = t1;
        partial[((long long)c * NB + blockIdx.x) * 2 + 1] = t2;
    }
}

// ---------------- finalize: mean, rstd per channel ----------------
__global__ void k_finalize(const double* __restrict__ partial, double* __restrict__ mr,
                           int C, double cnt) {
    int c = blockIdx.x * blockDim.x + threadIdx.x;
    if (c >= C) return;
    double s1 = 0.0, s2 = 0.0;
    for (int b = 0; b < NB; ++b) {
        s1 += partial[((long long)c * NB + b) * 2 + 0];
        s2 += partial[((long long)c * NB + b) * 2 + 1];
    }
    double mean = s1 / cnt;
    double var = s2 / cnt - mean * mean;
    double rstd = 1.0 / sqrt(var + 1e-5);
    mr[2 * c + 0] = mean;
    mr[2 * c + 1] = rstd;
}

// ---------------- sign(bn(x)) -> int8 ----------------
template <typename T>
__global__ void k_bnsign(const T* __restrict__ x, const double* __restrict__ mr,
                         const float* __restrict__ g, const float* __restrict__ b,
                         signed char* __restrict__ out, int C, int HW, long long total) {
    long long i = (long long)blockIdx.x * TPB + threadIdx.x;
    if (i >= total) return;
    int c = (int)((i / HW) % C);
    double xn = ((double)x[i] - mr[2 * c]) * mr[2 * c + 1];
    double v = xn * (double)g[c] + (double)b[c];
    out[i] = v > 0.0 ? 1 : (v < 0.0 ? -1 : 0);
}

// ---------------- fused conv(int8 x int8, stride1, VALID) + 3x3 maxpool(stride S) ----------------
// Block: 256 thr; tx=tid&15 -> 4 consecutive conv cols, ty=tid>>4 -> 16 conv rows.
// Conv tile 16 x 64 covers one pool tile PH x PW (S*PH+1 <= 16 rows, S*PW+1 <= 64 cols).
// Input tile in LDS (row stride 96B => 2-way bank aliasing = free). Weights are read
// directly from global with wave-uniform indices (scalar loads, K$-cached), padded to Kp.
template <int K, int COT, int S, int PH, int PW>
__global__ __launch_bounds__(256) void k_convpool(
    const signed char* __restrict__ a,   // [N][CI][H][W]
    const signed char* __restrict__ wp,  // [CO][CI][K][Kp]
    short* __restrict__ out,             // [N][CO][HOp][WOp]
    int CI, int H, int W, int CO, int HOp, int WOp) {
    constexpr int Kp = (K + 3) & ~3;
    constexpr int NC = Kp / 4;
    constexpr int R = NC + 1;
    constexpr int TH = 16 + K - 1;
    constexpr int TWB = 96;              // LDS row stride bytes (== 32 mod 64)
    extern __shared__ unsigned char lds[];
    unsigned char* in_t = lds;                        // CI*TH*TWB
    short* pool_t = (short*)(lds + CI * TH * TWB);    // [16][68]

    const int n = blockIdx.z;
    const int p0 = blockIdx.y * PH;      // pool tile origin
    const int q0 = blockIdx.x * PW;
    const int oh0 = p0 * S;              // conv tile origin
    const int ow0 = q0 * S;
    const int tid = threadIdx.x;
    const int tx = tid & 15, ty = tid >> 4;

    // ---- stage input tile (zero-fill out of bounds) ----
    const int tile_elems = CI * TH * TWB;
    for (int t = tid; t < tile_elems; t += TPB) {
        int x = t % TWB;
        int rest = t / TWB;
        int y = rest % TH;
        int ci = rest / TH;
        int gx = ow0 + x, gy = oh0 + y;
        signed char v = 0;
        if (gx < W && gy < H)
            v = a[((long long)(n * CI + ci) * H + gy) * W + gx];
        in_t[t] = (unsigned char)v;
    }
    __syncthreads();

    for (int co0 = 0; co0 < CO; co0 += COT) {
        int acc[COT][4];
#pragma unroll
        for (int co = 0; co < COT; ++co)
#pragma unroll
            for (int j = 0; j < 4; ++j) acc[co][j] = 0;

        for (int ci = 0; ci < CI; ++ci) {
#pragma unroll 1
            for (int kh = 0; kh < K; ++kh) {
                const unsigned int* ip =
                    (const unsigned int*)&in_t[(ci * TH + ty + kh) * TWB + tx * 4];
                unsigned int r[R];
#pragma unroll
                for (int i = 0; i < R; ++i) r[i] = ip[i];
                unsigned int av[NC][4];
#pragma unroll
                for (int c = 0; c < NC; ++c) {
                    av[c][0] = r[c];
                    av[c][1] = alignb(r[c + 1], r[c], 1);
                    av[c][2] = alignb(r[c + 1], r[c], 2);
                    av[c][3] = alignb(r[c + 1], r[c], 3);
                }
                // wave-uniform weight reads from global (scalar-loadable)
                const signed char* wrow = wp + ((long long)(co0) * CI + ci) * K * Kp + kh * Kp;
#pragma unroll
                for (int co = 0; co < COT; ++co) {
                    const unsigned int* wq =
                        (const unsigned int*)(wrow + (long long)co * CI * K * Kp);
#pragma unroll
                    for (int c = 0; c < NC; ++c) {
                        unsigned int w4 = wq[c];
                        acc[co][0] = dot4(av[c][0], w4, acc[co][0]);
                        acc[co][1] = dot4(av[c][1], w4, acc[co][1]);
                        acc[co][2] = dot4(av[c][2], w4, acc[co][2]);
                        acc[co][3] = dot4(av[c][3], w4, acc[co][3]);
                    }
                }
            }
        }

        // ---- pool each channel of this phase through LDS ----
#pragma unroll 1
        for (int co = 0; co < COT; ++co) {
            __syncthreads();  // previous co's pool reads done
            unsigned int lo = ((unsigned)acc[co][0] & 0xffffu) | ((unsigned)acc[co][1] << 16);
            unsigned int hi = ((unsigned)acc[co][2] & 0xffffu) | ((unsigned)acc[co][3] << 16);
            unsigned int* dst = (unsigned int*)&pool_t[ty * 68 + tx * 4];
            dst[0] = lo;
            dst[1] = hi;
            __syncthreads();
            constexpr int TOT = PH * PW;
#pragma unroll 1
            for (int t = tid; t < TOT; t += TPB) {
                int pp = t / PW, qq = t % PW;
                int p = p0 + pp, q = q0 + qq;
                if (p < HOp && q < WOp) {
                    const short* pt = &pool_t[(S * pp) * 68 + S * qq];
                    int m = pt[0];
                    m = max(m, (int)pt[1]); m = max(m, (int)pt[2]);
                    m = max(m, (int)pt[68]); m = max(m, (int)pt[69]); m = max(m, (int)pt[70]);
                    m = max(m, (int)pt[136]); m = max(m, (int)pt[137]); m = max(m, (int)pt[138]);
                    out[((long long)(n * CO + co0 + co) * HOp + p) * WOp + q] = (short)m;
                }
            }
        }
        __syncthreads();  // pool reads done before next phase rewrites pool_t
    }
}

// ---------------- simple direct conv (tiny last conv layer), padded weights ----------------
__global__ void k_conv(const signed char* __restrict__ a, const signed char* __restrict__ w,
                       short* __restrict__ out, int N, int CI, int HI, int WI,
                       int CO, int HO, int WO, int K, int Kp) {
    long long total = (long long)N * CO * HO * WO;
    long long idx = (long long)blockIdx.x * TPB + threadIdx.x;
    if (idx >= total) return;
    int ow = (int)(idx % WO);
    long long t = idx / WO;
    int oh = (int)(t % HO); t /= HO;
    int co = (int)(t % CO);
    int n = (int)(t / CO);
    int acc = 0;
    const signed char* wp = w + (long long)co * CI * K * Kp;
    for (int ci = 0; ci < CI; ++ci) {
        const signed char* ap = a + (((long long)n * CI + ci) * HI + oh) * WI + ow;
        for (int kh = 0; kh < K; ++kh) {
            for (int kw = 0; kw < K; ++kw)
                acc += (int)ap[kw] * (int)wp[kw];
            ap += WI;
            wp += Kp;
        }
    }
    out[idx] = (short)acc;
}

// ---------------- 3x3 maxpool, VALID, stride s ----------------
__global__ void k_pool(const short* __restrict__ in, short* __restrict__ out,
                       int NC, int HI, int WI, int HO, int WO, int s) {
    long long total = (long long)NC * HO * WO;
    long long idx = (long long)blockIdx.x * TPB + threadIdx.x;
    if (idx >= total) return;
    int ow = (int)(idx % WO);
    long long t = idx / WO;
    int oh = (int)(t % HO);
    int nc = (int)(t / HO);
    const short* p = in + ((long long)nc * HI + (long long)oh * s) * WI + (long long)ow * s;
    int m = -1000000;
    for (int kh = 0; kh < 3; ++kh) {
        m = max(m, (int)p[0]);
        m = max(m, (int)p[1]);
        m = max(m, (int)p[2]);
        p += WI;
    }
    out[idx] = (short)m;
}

// ---------------- FC: [64,256] int8 @ [50,256]^T int8 -> float ----------------
__global__ void k_fc(const signed char* __restrict__ a, const signed char* __restrict__ w,
                     float* __restrict__ out) {
    int i = blockIdx.x * TPB + threadIdx.x;
    if (i >= 64 * 50) return;
    int n = i / 50, c = i % 50;
    int acc = 0;
    for (int k = 0; k < 256; ++k)
        acc += (int)a[n * 256 + k] * (int)w[c * 256 + k];
    out[i] = (float)acc;
}

static inline long long cdiv(long long a, long long b) { return (a + b - 1) / b; }

extern "C" void kernel_launch(void* const* d_in, const int* in_sizes, int n_in,
                              void* d_out, int out_size, void* d_ws, size_t ws_size,
                              hipStream_t stream) {
    const float* x = (const float*)d_in[0];
    const float* gs[7] = {(const float*)d_in[1], (const float*)d_in[4], (const float*)d_in[7],
                          (const float*)d_in[10], (const float*)d_in[13], (const float*)d_in[16],
                          (const float*)d_in[19]};
    const float* bs[7] = {(const float*)d_in[2], (const float*)d_in[5], (const float*)d_in[8],
                          (const float*)d_in[11], (const float*)d_in[14], (const float*)d_in[17],
                          (const float*)d_in[20]};
    const float* wsrc[7] = {(const float*)d_in[3], (const float*)d_in[6], (const float*)d_in[9],
                            (const float*)d_in[12], (const float*)d_in[15], (const float*)d_in[18],
                            (const float*)d_in[21]};

    // layer geometry
    const int C_[7] = {3, 8, 16, 32, 32, 64, 64};       // bn channels (input of layer L)
    const int Hin[7] = {224, 212, 102, 48, 21, 8, 2};   // spatial of bn input
    const int CO_[6] = {8, 16, 32, 32, 64, 64};
    const int K_[6] = {11, 7, 5, 5, 5, 3};
    const int KP_[6] = {12, 8, 8, 8, 8, 4};
    const int PS_[6] = {1, 2, 2, 2, 2, 2};              // pool strides
    const int N = 64;

    // padded weight byte counts (+ FC plain)
    long long woff[7];
    {
        long long o = 0;
        for (int i = 0; i < 6; ++i) {
            woff[i] = o;
            o += (long long)CO_[i] * C_[i] * K_[i] * KP_[i];
            o = (o + 15) & ~15ll;
        }
        woff[6] = o;  // FC plain 50*256
    }

    // ---- workspace layout (~84 MB) ----
    char* ws = (char*)d_ws;
    double* partial = (double*)ws;                          // 256 KB
    double* mr = (double*)(ws + 262144);                    // 7*128 doubles
    signed char* wb = (signed char*)(ws + 278528);          // padded binarized weights (16B-aligned base)
    signed char* A = (signed char*)(ws + (1ll << 20));      // int8 activations, 24 MB slot
    short* Cb = (short*)(ws + (25ll << 20));                // conv out (L5 only), 12 MB slot
    short* Pb = (short*)(ws + (37ll << 20));                // pool out int16, 47 MB slot

    // binarize + pad conv weights; FC plain
    for (int i = 0; i < 6; ++i) {
        int total = CO_[i] * C_[i] * K_[i] * KP_[i];
        k_binwpad<<<dim3(cdiv(total, TPB)), TPB, 0, stream>>>(wsrc[i], wb + woff[i],
                                                              C_[i], K_[i], KP_[i], total);
    }
    k_binw<<<dim3(cdiv(50 * 256, TPB)), TPB, 0, stream>>>(wsrc[6], wb + woff[6], 50 * 256);

    const short* curP = nullptr;

    for (int L = 0; L < 7; ++L) {
        int C = C_[L], H = Hin[L], W = Hin[L];
        int HW = H * W;
        long long nhw = (long long)N * HW;
        long long tot = nhw * C;
        double* mrl = mr + L * 128;
        dim3 sg(NB, C);

        if (L == 0) {
            k_stats<float><<<sg, TPB, 0, stream>>>(x, N, C, HW, partial);
            k_finalize<<<1, 64, 0, stream>>>(partial, mrl, C, (double)nhw);
            k_bnsign<float><<<dim3(cdiv(tot, TPB)), TPB, 0, stream>>>(x, mrl, gs[L], bs[L], A, C, HW, tot);
        } else {
            k_stats<short><<<sg, TPB, 0, stream>>>(curP, N, C, HW, partial);
            k_finalize<<<1, 64, 0, stream>>>(partial, mrl, C, (double)nhw);
            k_bnsign<short><<<dim3(cdiv(tot, TPB)), TPB, 0, stream>>>(curP, mrl, gs[L], bs[L], A, C, HW, tot);
        }

        if (L == 6) {
            k_fc<<<dim3(cdiv(64 * 50, TPB)), TPB, 0, stream>>>(A, wb + woff[6], (float*)d_out);
            break;
        }

        int CO = CO_[L], K = K_[L];
        int HOc = H - K + 1, WOc = W - K + 1;
        int s = PS_[L];
        int HOp = (HOc - 3) / s + 1, WOp = (WOc - 3) / s + 1;

        if (L <= 4) {
            // fused conv+pool, full batch
            const int PH = (L == 0) ? 14 : 7;
            const int PW = (L == 0) ? 62 : 30;
            dim3 cg((unsigned)cdiv(WOp, PW), (unsigned)cdiv(HOp, PH), N);
            size_t lds = (size_t)C * (16 + K - 1) * 96 + 16 * 68 * sizeof(short);
            if (L == 0)
                k_convpool<11, 8, 1, 14, 62><<<cg, TPB, lds, stream>>>(A, wb + woff[L], Pb, C, H, W, CO, HOp, WOp);
            else if (L == 1)
                k_convpool<7, 16, 2, 7, 30><<<cg, TPB, lds, stream>>>(A, wb + woff[L], Pb, C, H, W, CO, HOp, WOp);
            else
                k_convpool<5, 16, 2, 7, 30><<<cg, TPB, lds, stream>>>(A, wb + woff[L], Pb, C, H, W, CO, HOp, WOp);
        } else {
            long long ctot = (long long)N * CO * HOc * WOc;
            k_conv<<<dim3(cdiv(ctot, TPB)), TPB, 0, stream>>>(A, wb + woff[L], Cb,
                                                              N, C, H, W, CO, HOc, WOc, K, KP_[L]);
            long long ptot = (long long)N * CO * HOp * WOp;
            k_pool<<<dim3(cdiv(ptot, TPB)), TPB, 0, stream>>>(Cb, Pb, N * CO, HOc, WOc, HOp, WOp, s);
        }
        curP = Pb;
    }
}

// Round 6
// 1583.450 us; speedup vs baseline: 8.3307x; 1.2607x over previous
//
#include <hip/hip_runtime.h>
#include <math.h>

#define TPB 256
#define NB 256  // stats blocks per channel

#if __has_builtin(__builtin_amdgcn_sdot4)
#define HAS_SDOT4 1
#else
#define HAS_SDOT4 0
#endif
#if __has_builtin(__builtin_amdgcn_alignbyte)
#define HAS_ALIGN 1
#else
#define HAS_ALIGN 0
#endif

__device__ __forceinline__ int dot4(unsigned int a, unsigned int b, int c) {
#if HAS_SDOT4
    return __builtin_amdgcn_sdot4((int)a, (int)b, c, false);
#else
    c += (int)(signed char)(a) * (int)(signed char)(b);
    c += (int)(signed char)(a >> 8) * (int)(signed char)(b >> 8);
    c += (int)(signed char)(a >> 16) * (int)(signed char)(b >> 16);
    c += (int)(signed char)(a >> 24) * (int)(signed char)(b >> 24);
    return c;
#endif
}

__device__ __forceinline__ unsigned int alignb(unsigned int hi, unsigned int lo, int s) {
#if HAS_ALIGN
    return (unsigned int)__builtin_amdgcn_alignbyte(hi, lo, s);
#else
    return (unsigned int)((((unsigned long long)hi << 32) | (unsigned long long)lo) >> (8 * s));
#endif
}

// ---------------- weight binarize (plain, for FC): sign(w) -> int8 ----------------
__global__ void k_binw(const float* __restrict__ w, signed char* __restrict__ wb, int n) {
    int i = blockIdx.x * TPB + threadIdx.x;
    if (i < n) {
        float v = w[i];
        wb[i] = v > 0.f ? 1 : (v < 0.f ? -1 : 0);
    }
}

// ---------------- weight binarize + pad rows to Kp: [CO][CI][K][K] -> [CO][CI][K][Kp] ----------------
__global__ void k_binwpad(const float* __restrict__ w, signed char* __restrict__ wb,
                          int CI, int K, int Kp, int total) {
    int i = blockIdx.x * TPB + threadIdx.x;
    if (i >= total) return;
    int kwp = i % Kp;
    int rest = i / Kp;          // (co*CI+ci)*K + kh
    signed char v = 0;
    if (kwp < K) {
        float f = w[rest * K + kwp];
        v = f > 0.f ? 1 : (f < 0.f ? -1 : 0);
    }
    wb[i] = v;
}

// ---------------- per-channel partial sum / sumsq (double, deterministic) ----------------
template <typename T>
__global__ void k_stats(const T* __restrict__ x, int N, int C, int HW,
                        double* __restrict__ partial /* [C][NB][2] */) {
    int c = blockIdx.y;
    long long total = (long long)N * HW;
    double s1 = 0.0, s2 = 0.0;
    long long stride = (long long)NB * TPB;
    for (long long i = (long long)blockIdx.x * TPB + threadIdx.x; i < total; i += stride) {
        int n = (int)(i / HW);
        int pos = (int)(i - (long long)n * HW);
        double v = (double)x[((long long)n * C + c) * HW + pos];
        s1 += v;
        s2 += v * v;
    }
    for (int off = 32; off > 0; off >>= 1) {
        s1 += __shfl_down(s1, off);
        s2 += __shfl_down(s2, off);
    }
    __shared__ double sh1[TPB / 64], sh2[TPB / 64];
    int wv = threadIdx.x >> 6;
    if ((threadIdx.x & 63) == 0) { sh1[wv] = s1; sh2[wv] = s2; }
    __syncthreads();
    if (threadIdx.x == 0) {
        double t1 = 0.0, t2 = 0.0;
        for (int i = 0; i < TPB / 64; ++i) { t1 += sh1[i]; t2 += sh2[i]; }
        partial[((long long)c * NB + blockIdx.x) * 2 + 0] = t1;
        partial[((long long)c * NB + blockIdx.x) * 2 + 1] = t2;
    }
}

// ---------------- finalize: mean, rstd per channel ----------------
__global__ void k_finalize(const double* __restrict__ partial, double* __restrict__ mr,
                           int C, double cnt) {
    int c = blockIdx.x * blockDim.x + threadIdx.x;
    if (c >= C) return;
    double s1 = 0.0, s2 = 0.0;
    for (int b = 0; b < NB; ++b) {
        s1 += partial[((long long)c * NB + b) * 2 + 0];
        s2 += partial[((long long)c * NB + b) * 2 + 1];
    }
    double mean = s1 / cnt;
    double var = s2 / cnt - mean * mean;
    double rstd = 1.0 / sqrt(var + 1e-5);
    mr[2 * c + 0] = mean;
    mr[2 * c + 1] = rstd;
}

// ---------------- sign(bn(x)) -> int8 ----------------
template <typename T>
__global__ void k_bnsign(const T* __restrict__ x, const double* __restrict__ mr,
                         const float* __restrict__ g, const float* __restrict__ b,
                         signed char* __restrict__ out, int C, int HW, long long total) {
    long long i = (long long)blockIdx.x * TPB + threadIdx.x;
    if (i >= total) return;
    int c = (int)((i / HW) % C);
    double xn = ((double)x[i] - mr[2 * c]) * mr[2 * c + 1];
    double v = xn * (double)g[c] + (double)b[c];
    out[i] = v > 0.0 ? 1 : (v < 0.0 ? -1 : 0);
}

// ---------------- fused conv(int8 x int8, stride1, VALID) + 3x3 maxpool(stride S) ----------------
// Block: 256 thr; tx=tid&15 -> 4 consecutive conv cols, ty=tid>>4 -> 16 conv rows.
// One co0-phase (COT channels) per block; phases split over blockIdx.z (z = n*NPH + ph).
// CI processed in chunks of CIC. Input chunk + weight chunk staged in LDS; weight reads
// are wave-uniform LDS broadcasts. Input row stride 96B (2-way bank aliasing = free).
template <int K, int COT, int S, int PH, int PW, int CIC>
__global__ __launch_bounds__(256, 4) void k_convpool(
    const signed char* __restrict__ a,   // [N][CI][H][W]
    const signed char* __restrict__ wp,  // [CO][CI][K][Kp]
    short* __restrict__ out,             // [N][CO][HOp][WOp]
    int CI, int H, int W, int CO, int HOp, int WOp, int NPH) {
    constexpr int Kp = (K + 3) & ~3;
    constexpr int NC = Kp / 4;
    constexpr int TH = 16 + K - 1;
    constexpr int TWB = 96, TWD = 24;    // LDS row stride: bytes / dwords
    extern __shared__ unsigned char lds[];
    unsigned char* in_t = lds;                                   // CIC*TH*TWB
    unsigned int* w_t = (unsigned int*)(lds + CIC * TH * TWB);   // COT*CIC*K*NC dwords
    short* pool_t = (short*)(lds + CIC * TH * TWB + COT * CIC * K * Kp);  // [16][68]

    const int z = blockIdx.z;
    const int n = z / NPH;
    const int co0 = (z - n * NPH) * COT;
    const int p0 = blockIdx.y * PH;      // pool tile origin
    const int q0 = blockIdx.x * PW;
    const int oh0 = p0 * S;              // conv tile origin (ow0 4-aligned by PW*S choice)
    const int ow0 = q0 * S;
    const int tid = threadIdx.x;
    const int tx = tid & 15, ty = tid >> 4;

    int acc[COT][4];
#pragma unroll
    for (int co = 0; co < COT; ++co)
#pragma unroll
        for (int j = 0; j < 4; ++j) acc[co][j] = 0;

    for (int ci0 = 0; ci0 < CI; ci0 += CIC) {
        __syncthreads();  // previous chunk's reads done before restaging
        // ---- stage input chunk (dword granularity, zero-fill OOB) ----
        for (int t = tid; t < CIC * TH * TWD; t += TPB) {
            int xd = t % TWD;
            int rest = t / TWD;
            int y = rest % TH;
            int ci = rest / TH;
            int gy = oh0 + y;
            int gx0 = ow0 + xd * 4;
            unsigned int v = 0;
            if (gy < H && gx0 < W) {
                const signed char* src =
                    a + ((long long)(n * CI + ci0 + ci) * H + gy) * W + gx0;
                if (gx0 + 3 < W) {
                    __builtin_memcpy(&v, src, 4);
                } else {
                    unsigned int b0 = 0, b1 = 0, b2 = 0;
                    b0 = (unsigned char)src[0];
                    if (gx0 + 1 < W) b1 = (unsigned char)src[1];
                    if (gx0 + 2 < W) b2 = (unsigned char)src[2];
                    v = b0 | (b1 << 8) | (b2 << 16);
                }
            }
            *(unsigned int*)&in_t[(ci * TH + y) * TWB + xd * 4] = v;
        }
        // ---- stage weight chunk [COT][CIC][K][NC] dwords ----
        constexpr int WTOT = COT * CIC * K * NC;
        for (int t = tid; t < WTOT; t += TPB) {
            int c = t % NC;
            int rest = t / NC;
            int kh = rest % K;
            rest /= K;
            int ci = rest % CIC;
            int co = rest / CIC;
            w_t[t] = ((const unsigned int*)wp)[(((long long)(co0 + co) * CI + ci0 + ci) * K + kh) * NC + c];
        }
        __syncthreads();

        const int cic = min(CIC, CI - ci0);
        for (int ci = 0; ci < cic; ++ci) {
#pragma unroll 1
            for (int kh = 0; kh < K; ++kh) {
                uint4 rr = *(const uint4*)&in_t[(ci * TH + ty + kh) * TWB + tx * 4];
                unsigned int r[4] = {rr.x, rr.y, rr.z, rr.w};
                unsigned int av[NC][4];
#pragma unroll
                for (int c = 0; c < NC; ++c) {
                    av[c][0] = r[c];
                    av[c][1] = alignb(r[c + 1], r[c], 1);
                    av[c][2] = alignb(r[c + 1], r[c], 2);
                    av[c][3] = alignb(r[c + 1], r[c], 3);
                }
                const unsigned int* wrow = &w_t[(ci * K + kh) * NC];
#pragma unroll
                for (int co = 0; co < COT; ++co) {
                    const unsigned int* wq = wrow + co * CIC * K * NC;
#pragma unroll
                    for (int c = 0; c < NC; ++c) {
                        unsigned int w4 = wq[c];
                        acc[co][0] = dot4(av[c][0], w4, acc[co][0]);
                        acc[co][1] = dot4(av[c][1], w4, acc[co][1]);
                        acc[co][2] = dot4(av[c][2], w4, acc[co][2]);
                        acc[co][3] = dot4(av[c][3], w4, acc[co][3]);
                    }
                }
            }
        }
    }

    // ---- pool each of the COT channels through LDS ----
#pragma unroll 1
    for (int co = 0; co < COT; ++co) {
        __syncthreads();  // previous co's pool reads done
        unsigned int lo = ((unsigned)acc[co][0] & 0xffffu) | ((unsigned)acc[co][1] << 16);
        unsigned int hi = ((unsigned)acc[co][2] & 0xffffu) | ((unsigned)acc[co][3] << 16);
        unsigned int* dst = (unsigned int*)&pool_t[ty * 68 + tx * 4];
        dst[0] = lo;
        dst[1] = hi;
        __syncthreads();
        constexpr int TOT = PH * PW;
#pragma unroll 1
        for (int t = tid; t < TOT; t += TPB) {
            int pp = t / PW, qq = t % PW;
            int p = p0 + pp, q = q0 + qq;
            if (p < HOp && q < WOp) {
                const short* pt = &pool_t[(S * pp) * 68 + S * qq];
                int m = pt[0];
                m = max(m, (int)pt[1]); m = max(m, (int)pt[2]);
                m = max(m, (int)pt[68]); m = max(m, (int)pt[69]); m = max(m, (int)pt[70]);
                m = max(m, (int)pt[136]); m = max(m, (int)pt[137]); m = max(m, (int)pt[138]);
                out[((long long)(n * CO + co0 + co) * HOp + p) * WOp + q] = (short)m;
            }
        }
    }
}

// ---------------- simple direct conv (tiny last conv layer), padded weights ----------------
__global__ void k_conv(const signed char* __restrict__ a, const signed char* __restrict__ w,
                       short* __restrict__ out, int N, int CI, int HI, int WI,
                       int CO, int HO, int WO, int K, int Kp) {
    long long total = (long long)N * CO * HO * WO;
    long long idx = (long long)blockIdx.x * TPB + threadIdx.x;
    if (idx >= total) return;
    int ow = (int)(idx % WO);
    long long t = idx / WO;
    int oh = (int)(t % HO); t /= HO;
    int co = (int)(t % CO);
    int n = (int)(t / CO);
    int acc = 0;
    const signed char* wp = w + (long long)co * CI * K * Kp;
    for (int ci = 0; ci < CI; ++ci) {
        const signed char* ap = a + (((long long)n * CI + ci) * HI + oh) * WI + ow;
        for (int kh = 0; kh < K; ++kh) {
            for (int kw = 0; kw < K; ++kw)
                acc += (int)ap[kw] * (int)wp[kw];
            ap += WI;
            wp += Kp;
        }
    }
    out[idx] = (short)acc;
}

// ---------------- 3x3 maxpool, VALID, stride s ----------------
__global__ void k_pool(const short* __restrict__ in, short* __restrict__ out,
                       int NC, int HI, int WI, int HO, int WO, int s) {
    long long total = (long long)NC * HO * WO;
    long long idx = (long long)blockIdx.x * TPB + threadIdx.x;
    if (idx >= total) return;
    int ow = (int)(idx % WO);
    long long t = idx / WO;
    int oh = (int)(t % HO);
    int nc = (int)(t / HO);
    const short* p = in + ((long long)nc * HI + (long long)oh * s) * WI + (long long)ow * s;
    int m = -1000000;
    for (int kh = 0; kh < 3; ++kh) {
        m = max(m, (int)p[0]);
        m = max(m, (int)p[1]);
        m = max(m, (int)p[2]);
        p += WI;
    }
    out[idx] = (short)m;
}

// ---------------- FC: [64,256] int8 @ [50,256]^T int8 -> float ----------------
__global__ void k_fc(const signed char* __restrict__ a, const signed char* __restrict__ w,
                     float* __restrict__ out) {
    int i = blockIdx.x * TPB + threadIdx.x;
    if (i >= 64 * 50) return;
    int n = i / 50, c = i % 50;
    int acc = 0;
    for (int k = 0; k < 256; ++k)
        acc += (int)a[n * 256 + k] * (int)w[c * 256 + k];
    out[i] = (float)acc;
}

static inline long long cdiv(long long a, long long b) { return (a + b - 1) / b; }

extern "C" void kernel_launch(void* const* d_in, const int* in_sizes, int n_in,
                              void* d_out, int out_size, void* d_ws, size_t ws_size,
                              hipStream_t stream) {
    const float* x = (const float*)d_in[0];
    const float* gs[7] = {(const float*)d_in[1], (const float*)d_in[4], (const float*)d_in[7],
                          (const float*)d_in[10], (const float*)d_in[13], (const float*)d_in[16],
                          (const float*)d_in[19]};
    const float* bs[7] = {(const float*)d_in[2], (const float*)d_in[5], (const float*)d_in[8],
                          (const float*)d_in[11], (const float*)d_in[14], (const float*)d_in[17],
                          (const float*)d_in[20]};
    const float* wsrc[7] = {(const float*)d_in[3], (const float*)d_in[6], (const float*)d_in[9],
                            (const float*)d_in[12], (const float*)d_in[15], (const float*)d_in[18],
                            (const float*)d_in[21]};

    // layer geometry
    const int C_[7] = {3, 8, 16, 32, 32, 64, 64};       // bn channels (input of layer L)
    const int Hin[7] = {224, 212, 102, 48, 21, 8, 2};   // spatial of bn input
    const int CO_[6] = {8, 16, 32, 32, 64, 64};
    const int K_[6] = {11, 7, 5, 5, 5, 3};
    const int KP_[6] = {12, 8, 8, 8, 8, 4};
    const int PS_[6] = {1, 2, 2, 2, 2, 2};              // pool strides
    const int N = 64;

    long long woff[7];
    {
        long long o = 0;
        for (int i = 0; i < 6; ++i) {
            woff[i] = o;
            o += (long long)CO_[i] * C_[i] * K_[i] * KP_[i];
            o = (o + 15) & ~15ll;
        }
        woff[6] = o;  // FC plain 50*256
    }

    // ---- workspace layout (~84 MB) ----
    char* ws = (char*)d_ws;
    double* partial = (double*)ws;                          // 256 KB
    double* mr = (double*)(ws + 262144);                    // 7*128 doubles
    signed char* wb = (signed char*)(ws + 278528);          // padded binarized weights (16B aligned)
    signed char* A = (signed char*)(ws + (1ll << 20));      // int8 activations, 24 MB slot
    short* Cb = (short*)(ws + (25ll << 20));                // conv out (L5 only), 12 MB slot
    short* Pb = (short*)(ws + (37ll << 20));                // pool out int16, 47 MB slot

    for (int i = 0; i < 6; ++i) {
        int total = CO_[i] * C_[i] * K_[i] * KP_[i];
        k_binwpad<<<dim3(cdiv(total, TPB)), TPB, 0, stream>>>(wsrc[i], wb + woff[i],
                                                              C_[i], K_[i], KP_[i], total);
    }
    k_binw<<<dim3(cdiv(50 * 256, TPB)), TPB, 0, stream>>>(wsrc[6], wb + woff[6], 50 * 256);

    const short* curP = nullptr;

    for (int L = 0; L < 7; ++L) {
        int C = C_[L], H = Hin[L], W = Hin[L];
        int HW = H * W;
        long long nhw = (long long)N * HW;
        long long tot = nhw * C;
        double* mrl = mr + L * 128;
        dim3 sg(NB, C);

        if (L == 0) {
            k_stats<float><<<sg, TPB, 0, stream>>>(x, N, C, HW, partial);
            k_finalize<<<1, 64, 0, stream>>>(partial, mrl, C, (double)nhw);
            k_bnsign<float><<<dim3(cdiv(tot, TPB)), TPB, 0, stream>>>(x, mrl, gs[L], bs[L], A, C, HW, tot);
        } else {
            k_stats<short><<<sg, TPB, 0, stream>>>(curP, N, C, HW, partial);
            k_finalize<<<1, 64, 0, stream>>>(partial, mrl, C, (double)nhw);
            k_bnsign<short><<<dim3(cdiv(tot, TPB)), TPB, 0, stream>>>(curP, mrl, gs[L], bs[L], A, C, HW, tot);
        }

        if (L == 6) {
            k_fc<<<dim3(cdiv(64 * 50, TPB)), TPB, 0, stream>>>(A, wb + woff[6], (float*)d_out);
            break;
        }

        int CO = CO_[L], K = K_[L];
        int HOc = H - K + 1, WOc = W - K + 1;
        int s = PS_[L];
        int HOp = (HOc - 3) / s + 1, WOp = (WOc - 3) / s + 1;

        if (L <= 4) {
            const int COT = 8;
            int NPH = CO / COT;
            const int PH = (L == 0) ? 14 : 7;
            const int PW = (L == 0) ? 60 : 30;
            dim3 cg((unsigned)cdiv(WOp, PW), (unsigned)cdiv(HOp, PH), (unsigned)(N * NPH));
            const int CIC = (L >= 3) ? 16 : C;
            size_t lds = (size_t)CIC * (16 + K - 1) * 96 + (size_t)COT * CIC * K * KP_[L] + 16 * 68 * sizeof(short);
            if (L == 0)
                k_convpool<11, 8, 1, 14, 60, 3><<<cg, TPB, lds, stream>>>(A, wb + woff[L], Pb, C, H, W, CO, HOp, WOp, NPH);
            else if (L == 1)
                k_convpool<7, 8, 2, 7, 30, 8><<<cg, TPB, lds, stream>>>(A, wb + woff[L], Pb, C, H, W, CO, HOp, WOp, NPH);
            else if (L == 2)
                k_convpool<5, 8, 2, 7, 30, 16><<<cg, TPB, lds, stream>>>(A, wb + woff[L], Pb, C, H, W, CO, HOp, WOp, NPH);
            else
                k_convpool<5, 8, 2, 7, 30, 16><<<cg, TPB, lds, stream>>>(A, wb + woff[L], Pb, C, H, W, CO, HOp, WOp, NPH);
        } else {
            long long ctot = (long long)N * CO * HOc * WOc;
            k_conv<<<dim3(cdiv(ctot, TPB)), TPB, 0, stream>>>(A, wb + woff[L], Cb,
                                                              N, C, H, W, CO, HOc, WOc, K, KP_[L]);
            long long ptot = (long long)N * CO * HOp * WOp;
            k_pool<<<dim3(cdiv(ptot, TPB)), TPB, 0, stream>>>(Cb, Pb, N * CO, HOc, WOc, HOp, WOp, s);
        }
        curP = Pb;
    }
}

// Round 8
// 1404.549 us; speedup vs baseline: 9.3918x; 1.1274x over previous
//
#include <hip/hip_runtime.h>
#include <math.h>

#define TPB 256

#if __has_builtin(__builtin_amdgcn_sdot4)
#define HAS_SDOT4 1
#else
#define HAS_SDOT4 0
#endif
#if __has_builtin(__builtin_amdgcn_alignbyte)
#define HAS_ALIGN 1
#else
#define HAS_ALIGN 0
#endif

__device__ __forceinline__ int dot4(unsigned int a, unsigned int b, int c) {
#if HAS_SDOT4
    return __builtin_amdgcn_sdot4((int)a, (int)b, c, false);
#else
    c += (int)(signed char)(a) * (int)(signed char)(b);
    c += (int)(signed char)(a >> 8) * (int)(signed char)(b >> 8);
    c += (int)(signed char)(a >> 16) * (int)(signed char)(b >> 16);
    c += (int)(signed char)(a >> 24) * (int)(signed char)(b >> 24);
    return c;
#endif
}

__device__ __forceinline__ unsigned int alignb(unsigned int hi, unsigned int lo, int s) {
#if HAS_ALIGN
    return (unsigned int)__builtin_amdgcn_alignbyte(hi, lo, s);
#else
    return (unsigned int)((((unsigned long long)hi << 32) | (unsigned long long)lo) >> (8 * s));
#endif
}

// ---------------- weight binarize (plain, for FC) ----------------
__global__ void k_binw(const float* __restrict__ w, signed char* __restrict__ wb, int n) {
    int i = blockIdx.x * TPB + threadIdx.x;
    if (i < n) {
        float v = w[i];
        wb[i] = v > 0.f ? 1 : (v < 0.f ? -1 : 0);
    }
}

// ---------------- weight binarize + pad rows to Kp ----------------
__global__ void k_binwpad(const float* __restrict__ w, signed char* __restrict__ wb,
                          int CI, int K, int Kp, int total) {
    int i = blockIdx.x * TPB + threadIdx.x;
    if (i >= total) return;
    int kwp = i % Kp;
    int rest = i / Kp;          // (co*CI+ci)*K + kh
    signed char v = 0;
    if (kwp < K) {
        float f = w[rest * K + kwp];
        v = f > 0.f ? 1 : (f < 0.f ? -1 : 0);
    }
    wb[i] = v;
}

// ---------------- per-channel partial sum / sumsq (double, deterministic, div-free) ----------------
template <typename T, int V>
__global__ void k_stats(const T* __restrict__ x, int N, int C, int HW,
                        double* __restrict__ partial, int NBX) {
    int c = blockIdx.y;
    double s1 = 0.0, s2 = 0.0;
    const long long step = (long long)gridDim.x * TPB * V;
    for (int n = 0; n < N; ++n) {
        const T* xp = x + ((long long)n * C + c) * HW;
        for (long long p = ((long long)blockIdx.x * TPB + threadIdx.x) * V; p + V <= HW; p += step) {
            T buf[V];
            __builtin_memcpy(buf, xp + p, V * sizeof(T));
#pragma unroll
            for (int j = 0; j < V; ++j) {
                double v = (double)buf[j];
                s1 += v;
                s2 += v * v;
            }
        }
    }
    for (int off = 32; off > 0; off >>= 1) {
        s1 += __shfl_down(s1, off);
        s2 += __shfl_down(s2, off);
    }
    __shared__ double sh1[TPB / 64], sh2[TPB / 64];
    int wv = threadIdx.x >> 6;
    if ((threadIdx.x & 63) == 0) { sh1[wv] = s1; sh2[wv] = s2; }
    __syncthreads();
    if (threadIdx.x == 0) {
        double t1 = 0.0, t2 = 0.0;
        for (int i = 0; i < TPB / 64; ++i) { t1 += sh1[i]; t2 += sh2[i]; }
        partial[((long long)c * NBX + blockIdx.x) * 2 + 0] = t1;
        partial[((long long)c * NBX + blockIdx.x) * 2 + 1] = t2;
    }
}

// ---------------- finalize: mean, rstd per channel ----------------
__global__ void k_finalize(const double* __restrict__ partial, double* __restrict__ mr,
                           int C, double cnt, int NBX) {
    int c = blockIdx.x * blockDim.x + threadIdx.x;
    if (c >= C) return;
    double s1 = 0.0, s2 = 0.0;
    for (int b = 0; b < NBX; ++b) {
        s1 += partial[((long long)c * NBX + b) * 2 + 0];
        s2 += partial[((long long)c * NBX + b) * 2 + 1];
    }
    double mean = s1 / cnt;
    double var = s2 / cnt - mean * mean;
    double rstd = 1.0 / sqrt(var + 1e-5);
    mr[2 * c + 0] = mean;
    mr[2 * c + 1] = rstd;
}

// ---------------- sign(bn(x)) -> int8 (div-free, vectorized) ----------------
template <typename T, int V>
__global__ void k_bnsign(const T* __restrict__ x, const double* __restrict__ mr,
                         const float* __restrict__ g, const float* __restrict__ b,
                         signed char* __restrict__ out, int C, int HW) {
    const int c = blockIdx.y;
    const int n = blockIdx.z;
    const double mean = mr[2 * c], rstd = mr[2 * c + 1];
    const double gg = (double)g[c], bb = (double)b[c];
    const T* xp = x + ((long long)n * C + c) * HW;
    signed char* op = out + ((long long)n * C + c) * HW;
    long long p = ((long long)blockIdx.x * TPB + threadIdx.x) * V;
    if (p + V > HW) {
        for (; p < HW; ++p) {
            double v = ((double)xp[p] - mean) * rstd * gg + bb;
            op[p] = v > 0.0 ? 1 : (v < 0.0 ? -1 : 0);
        }
        return;
    }
    T buf[V];
    __builtin_memcpy(buf, xp + p, V * sizeof(T));
    signed char o[V];
#pragma unroll
    for (int j = 0; j < V; ++j) {
        double v = ((double)buf[j] - mean) * rstd * gg + bb;
        o[j] = v > 0.0 ? 1 : (v < 0.0 ? -1 : 0);
    }
    __builtin_memcpy(op + p, o, V);
}

// ---------------- fused conv(int8 x int8, stride1, VALID) + 3x3 maxpool(stride S) ----------------
// Block: 256 thr; tx=tid&15 -> 4 consecutive conv cols, ty=tid>>4 -> 16 conv rows.
// One co0-phase (COT channels) per block; z = n*NPH + ph. CI in chunks of CIC.
// Input chunk in LDS (row stride 96B: 2-way bank aliasing = free).
// Weights in LDS laid out [ci][kh][co][NC] so each (ci,kh) loads as aligned
// ds_read_b128 broadcasts into registers (4-6 LDS issues instead of 16-24).
template <int K, int COT, int S, int PH, int PW, int CIC>
__global__ __launch_bounds__(256, 4) void k_convpool(
    const signed char* __restrict__ a,   // [N][CI][H][W]
    const signed char* __restrict__ wp,  // [CO][CI][K][Kp] (dword rows)
    short* __restrict__ out,             // [N][CO][HOp][WOp]
    int CI, int H, int W, int CO, int HOp, int WOp, int NPH) {
    constexpr int Kp = (K + 3) & ~3;
    constexpr int NC = Kp / 4;
    constexpr int TH = 16 + K - 1;
    constexpr int TWB = 96, TWD = 24;    // LDS input row stride: bytes / dwords
    constexpr int WSTR = COT * NC;       // weight dwords per (ci,kh)
    extern __shared__ unsigned char lds[];
    unsigned char* in_t = lds;                                   // CIC*TH*TWB bytes
    unsigned int* w_t = (unsigned int*)(lds + CIC * TH * TWB);   // CIC*K*WSTR dwords
    short* pool_t = (short*)(lds + CIC * TH * TWB + CIC * K * WSTR * 4);  // [16][68]

    const int z = blockIdx.z;
    const int n = z / NPH;
    const int co0 = (z - n * NPH) * COT;
    const int p0 = blockIdx.y * PH;      // pool tile origin
    const int q0 = blockIdx.x * PW;
    const int oh0 = p0 * S;              // conv tile origin
    const int ow0 = q0 * S;              // 4-aligned by PW*S choice
    const int tid = threadIdx.x;
    const int tx = tid & 15, ty = tid >> 4;

    int acc[COT][4];
#pragma unroll
    for (int co = 0; co < COT; ++co)
#pragma unroll
        for (int j = 0; j < 4; ++j) acc[co][j] = 0;

    for (int ci0 = 0; ci0 < CI; ci0 += CIC) {
        __syncthreads();  // previous chunk's reads done before restaging
        // ---- stage input chunk (dword granularity, zero-fill OOB) ----
        for (int t = tid; t < CIC * TH * TWD; t += TPB) {
            int xd = t % TWD;
            int rest = t / TWD;
            int y = rest % TH;
            int ci = rest / TH;
            int gy = oh0 + y;
            int gx0 = ow0 + xd * 4;
            unsigned int v = 0;
            if (gy < H && gx0 < W) {
                const signed char* src =
                    a + ((long long)(n * CI + ci0 + ci) * H + gy) * W + gx0;
                if (gx0 + 3 < W) {
                    __builtin_memcpy(&v, src, 4);
                } else {
                    unsigned int b0 = (unsigned char)src[0], b1 = 0, b2 = 0;
                    if (gx0 + 1 < W) b1 = (unsigned char)src[1];
                    if (gx0 + 2 < W) b2 = (unsigned char)src[2];
                    v = b0 | (b1 << 8) | (b2 << 16);
                }
            }
            *(unsigned int*)&in_t[(ci * TH + y) * TWB + xd * 4] = v;
        }
        // ---- stage weight chunk, layout [ci][kh][co][NC] dwords ----
        constexpr int WTOT = CIC * K * WSTR;
        for (int t = tid; t < WTOT; t += TPB) {
            int c = t % NC;
            int rest = t / NC;
            int co = rest % COT;
            rest /= COT;
            int kh = rest % K;
            int ci = rest / K;
            w_t[t] = ((const unsigned int*)wp)[(((long long)(co0 + co) * CI + ci0 + ci) * K + kh) * NC + c];
        }
        __syncthreads();

        for (int ci = 0; ci < CIC; ++ci) {
#pragma unroll 1
            for (int kh = 0; kh < K; ++kh) {
                uint4 rr = *(const uint4*)&in_t[(ci * TH + ty + kh) * TWB + tx * 4];
                unsigned int r[4] = {rr.x, rr.y, rr.z, rr.w};
                // weights: aligned b128 broadcasts into registers
                unsigned int wreg[WSTR];
                const uint4* wsrc = (const uint4*)&w_t[(ci * K + kh) * WSTR];
#pragma unroll
                for (int i = 0; i < WSTR / 4; ++i) *(uint4*)&wreg[4 * i] = wsrc[i];
                unsigned int av[NC][4];
#pragma unroll
                for (int c = 0; c < NC; ++c) {
                    av[c][0] = r[c];
                    av[c][1] = alignb(r[c + 1], r[c], 1);
                    av[c][2] = alignb(r[c + 1], r[c], 2);
                    av[c][3] = alignb(r[c + 1], r[c], 3);
                }
#pragma unroll
                for (int co = 0; co < COT; ++co) {
#pragma unroll
                    for (int c = 0; c < NC; ++c) {
                        unsigned int w4 = wreg[co * NC + c];
                        acc[co][0] = dot4(av[c][0], w4, acc[co][0]);
                        acc[co][1] = dot4(av[c][1], w4, acc[co][1]);
                        acc[co][2] = dot4(av[c][2], w4, acc[co][2]);
                        acc[co][3] = dot4(av[c][3], w4, acc[co][3]);
                    }
                }
            }
        }
    }

    // ---- pool each of the COT channels through LDS ----
#pragma unroll 1
    for (int co = 0; co < COT; ++co) {
        __syncthreads();  // previous co's pool reads done
        unsigned int lo = ((unsigned)acc[co][0] & 0xffffu) | ((unsigned)acc[co][1] << 16);
        unsigned int hi = ((unsigned)acc[co][2] & 0xffffu) | ((unsigned)acc[co][3] << 16);
        unsigned int* dst = (unsigned int*)&pool_t[ty * 68 + tx * 4];
        dst[0] = lo;
        dst[1] = hi;
        __syncthreads();
        constexpr int TOT = PH * PW;
#pragma unroll 1
        for (int t = tid; t < TOT; t += TPB) {
            int pp = t / PW, qq = t % PW;
            int p = p0 + pp, q = q0 + qq;
            if (p < HOp && q < WOp) {
                const short* pt = &pool_t[(S * pp) * 68 + S * qq];
                int m = pt[0];
                m = max(m, (int)pt[1]); m = max(m, (int)pt[2]);
                m = max(m, (int)pt[68]); m = max(m, (int)pt[69]); m = max(m, (int)pt[70]);
                m = max(m, (int)pt[136]); m = max(m, (int)pt[137]); m = max(m, (int)pt[138]);
                out[((long long)(n * CO + co0 + co) * HOp + p) * WOp + q] = (short)m;
            }
        }
    }
}

// ---------------- FC: [64,256] int8 @ [50,256]^T int8 -> float ----------------
__global__ void k_fc(const signed char* __restrict__ a, const signed char* __restrict__ w,
                     float* __restrict__ out) {
    int i = blockIdx.x * TPB + threadIdx.x;
    if (i >= 64 * 50) return;
    int n = i / 50, c = i % 50;
    int acc = 0;
    for (int k = 0; k < 256; ++k)
        acc += (int)a[n * 256 + k] * (int)w[c * 256 + k];
    out[i] = (float)acc;
}

static inline long long cdiv(long long a, long long b) { return (a + b - 1) / b; }

extern "C" void kernel_launch(void* const* d_in, const int* in_sizes, int n_in,
                              void* d_out, int out_size, void* d_ws, size_t ws_size,
                              hipStream_t stream) {
    const float* x = (const float*)d_in[0];
    const float* gs[7] = {(const float*)d_in[1], (const float*)d_in[4], (const float*)d_in[7],
                          (const float*)d_in[10], (const float*)d_in[13], (const float*)d_in[16],
                          (const float*)d_in[19]};
    const float* bs[7] = {(const float*)d_in[2], (const float*)d_in[5], (const float*)d_in[8],
                          (const float*)d_in[11], (const float*)d_in[14], (const float*)d_in[17],
                          (const float*)d_in[20]};
    const float* wsrc[7] = {(const float*)d_in[3], (const float*)d_in[6], (const float*)d_in[9],
                            (const float*)d_in[12], (const float*)d_in[15], (const float*)d_in[18],
                            (const float*)d_in[21]};

    // layer geometry
    const int C_[7] = {3, 8, 16, 32, 32, 64, 64};       // bn channels (input of layer L)
    const int Hin[7] = {224, 212, 102, 48, 21, 8, 2};   // spatial of bn input
    const int CO_[6] = {8, 16, 32, 32, 64, 64};
    const int K_[6] = {11, 7, 5, 5, 5, 3};
    const int KP_[6] = {12, 8, 8, 8, 8, 4};
    const int PS_[6] = {1, 2, 2, 2, 2, 2};
    const int PH_[6] = {14, 7, 7, 7, 7, 2};
    const int PW_[6] = {60, 30, 30, 30, 30, 2};
    const int CIC_[6] = {3, 8, 16, 16, 16, 16};
    const int N = 64;

    long long woff[7];
    {
        long long o = 0;
        for (int i = 0; i < 6; ++i) {
            woff[i] = o;
            o += (long long)CO_[i] * C_[i] * K_[i] * KP_[i];
            o = (o + 15) & ~15ll;
        }
        woff[6] = o;  // FC plain 50*256
    }

    // ---- workspace layout (~84 MB) ----
    char* ws = (char*)d_ws;
    double* partial = (double*)ws;                          // 256 KB
    double* mr = (double*)(ws + 262144);                    // 7*128 doubles
    signed char* wb = (signed char*)(ws + 278528);          // padded binarized weights (16B aligned)
    signed char* A = (signed char*)(ws + (1ll << 20));      // int8 activations, 24 MB slot
    short* Pb = (short*)(ws + (37ll << 20));                // pool out int16, 47 MB slot

    for (int i = 0; i < 6; ++i) {
        int total = CO_[i] * C_[i] * K_[i] * KP_[i];
        k_binwpad<<<dim3(cdiv(total, TPB)), TPB, 0, stream>>>(wsrc[i], wb + woff[i],
                                                              C_[i], K_[i], KP_[i], total);
    }
    k_binw<<<dim3(cdiv(50 * 256, TPB)), TPB, 0, stream>>>(wsrc[6], wb + woff[6], 50 * 256);

    const short* curP = nullptr;

    for (int L = 0; L < 7; ++L) {
        int C = C_[L], H = Hin[L], W = Hin[L];
        int HW = H * W;
        long long nhw = (long long)N * HW;
        double* mrl = mr + L * 128;
        const int V = (HW % 4 == 0) ? 4 : 1;
        int gsx = (int)min((long long)256, cdiv(HW, (long long)TPB * V));
        dim3 sg((unsigned)gsx, C);
        dim3 bg((unsigned)cdiv(HW, (long long)TPB * V), C, N);

        if (L == 0) {
            if (V == 4) {
                k_stats<float, 4><<<sg, TPB, 0, stream>>>(x, N, C, HW, partial, gsx);
                k_finalize<<<1, 64, 0, stream>>>(partial, mrl, C, (double)nhw, gsx);
                k_bnsign<float, 4><<<bg, TPB, 0, stream>>>(x, mrl, gs[L], bs[L], A, C, HW);
            } else {
                k_stats<float, 1><<<sg, TPB, 0, stream>>>(x, N, C, HW, partial, gsx);
                k_finalize<<<1, 64, 0, stream>>>(partial, mrl, C, (double)nhw, gsx);
                k_bnsign<float, 1><<<bg, TPB, 0, stream>>>(x, mrl, gs[L], bs[L], A, C, HW);
            }
        } else {
            if (V == 4) {
                k_stats<short, 4><<<sg, TPB, 0, stream>>>(curP, N, C, HW, partial, gsx);
                k_finalize<<<1, 64, 0, stream>>>(partial, mrl, C, (double)nhw, gsx);
                k_bnsign<short, 4><<<bg, TPB, 0, stream>>>(curP, mrl, gs[L], bs[L], A, C, HW);
            } else {
                k_stats<short, 1><<<sg, TPB, 0, stream>>>(curP, N, C, HW, partial, gsx);
                k_finalize<<<1, 64, 0, stream>>>(partial, mrl, C, (double)nhw, gsx);
                k_bnsign<short, 1><<<bg, TPB, 0, stream>>>(curP, mrl, gs[L], bs[L], A, C, HW);
            }
        }

        if (L == 6) {
            k_fc<<<dim3(cdiv(64 * 50, TPB)), TPB, 0, stream>>>(A, wb + woff[6], (float*)d_out);
            break;
        }

        int CO = CO_[L], K = K_[L];
        int HOc = H - K + 1;
        int s = PS_[L];
        int HOp = (HOc - 3) / s + 1, WOp = HOp;

        const int COT = 8;
        int NPH = CO / COT;
        dim3 cg((unsigned)cdiv(WOp, PW_[L]), (unsigned)cdiv(HOp, PH_[L]), (unsigned)(N * NPH));
        size_t lds = (size_t)CIC_[L] * (16 + K - 1) * 96 +
                     (size_t)CIC_[L] * K_[L] * COT * KP_[L] + 16 * 68 * sizeof(short);
        switch (L) {
            case 0: k_convpool<11, 8, 1, 14, 60, 3><<<cg, TPB, lds, stream>>>(A, wb + woff[L], Pb, C, H, W, CO, HOp, WOp, NPH); break;
            case 1: k_convpool<7, 8, 2, 7, 30, 8><<<cg, TPB, lds, stream>>>(A, wb + woff[L], Pb, C, H, W, CO, HOp, WOp, NPH); break;
            case 2: k_convpool<5, 8, 2, 7, 30, 16><<<cg, TPB, lds, stream>>>(A, wb + woff[L], Pb, C, H, W, CO, HOp, WOp, NPH); break;
            case 3: k_convpool<5, 8, 2, 7, 30, 16><<<cg, TPB, lds, stream>>>(A, wb + woff[L], Pb, C, H, W, CO, HOp, WOp, NPH); break;
            case 4: k_convpool<5, 8, 2, 7, 30, 16><<<cg, TPB, lds, stream>>>(A, wb + woff[L], Pb, C, H, W, CO, HOp, WOp, NPH); break;
            case 5: k_convpool<3, 8, 2, 2, 2, 16><<<cg, TPB, lds, stream>>>(A, wb + woff[L], Pb, C, H, W, CO, HOp, WOp, NPH); break;
        }
        curP = Pb;
    }
}

// Round 9
// 1387.528 us; speedup vs baseline: 9.5070x; 1.0123x over previous
//
#include <hip/hip_runtime.h>
#include <math.h>

#define TPB 256

#if __has_builtin(__builtin_amdgcn_sdot4)
#define HAS_SDOT4 1
#else
#define HAS_SDOT4 0
#endif
#if __has_builtin(__builtin_amdgcn_alignbyte)
#define HAS_ALIGN 1
#else
#define HAS_ALIGN 0
#endif

__device__ __forceinline__ int dot4(unsigned int a, unsigned int b, int c) {
#if HAS_SDOT4
    return __builtin_amdgcn_sdot4((int)a, (int)b, c, false);
#else
    c += (int)(signed char)(a) * (int)(signed char)(b);
    c += (int)(signed char)(a >> 8) * (int)(signed char)(b >> 8);
    c += (int)(signed char)(a >> 16) * (int)(signed char)(b >> 16);
    c += (int)(signed char)(a >> 24) * (int)(signed char)(b >> 24);
    return c;
#endif
}

__device__ __forceinline__ unsigned int alignb(unsigned int hi, unsigned int lo, int s) {
#if HAS_ALIGN
    return (unsigned int)__builtin_amdgcn_alignbyte(hi, lo, s);
#else
    return (unsigned int)((((unsigned long long)hi << 32) | (unsigned long long)lo) >> (8 * s));
#endif
}

// ---------------- weight binarize (plain, for FC) ----------------
__global__ void k_binw(const float* __restrict__ w, signed char* __restrict__ wb, int n) {
    int i = blockIdx.x * TPB + threadIdx.x;
    if (i < n) {
        float v = w[i];
        wb[i] = v > 0.f ? 1 : (v < 0.f ? -1 : 0);
    }
}

// ---------------- weight binarize + pad rows to Kp ----------------
__global__ void k_binwpad(const float* __restrict__ w, signed char* __restrict__ wb,
                          int CI, int K, int Kp, int total) {
    int i = blockIdx.x * TPB + threadIdx.x;
    if (i >= total) return;
    int kwp = i % Kp;
    int rest = i / Kp;          // (co*CI+ci)*K + kh
    signed char v = 0;
    if (kwp < K) {
        float f = w[rest * K + kwp];
        v = f > 0.f ? 1 : (f < 0.f ? -1 : 0);
    }
    wb[i] = v;
}

// ---------------- per-channel partial sum / sumsq (double, deterministic, div-free) ----------------
template <typename T, int V>
__global__ void k_stats(const T* __restrict__ x, int N, int C, int HW,
                        double* __restrict__ partial, int NBX) {
    int c = blockIdx.y;
    double s1 = 0.0, s2 = 0.0;
    const long long step = (long long)gridDim.x * TPB * V;
    for (int n = 0; n < N; ++n) {
        const T* xp = x + ((long long)n * C + c) * HW;
        for (long long p = ((long long)blockIdx.x * TPB + threadIdx.x) * V; p + V <= HW; p += step) {
            T buf[V];
            __builtin_memcpy(buf, xp + p, V * sizeof(T));
#pragma unroll
            for (int j = 0; j < V; ++j) {
                double v = (double)buf[j];
                s1 += v;
                s2 += v * v;
            }
        }
    }
    for (int off = 32; off > 0; off >>= 1) {
        s1 += __shfl_down(s1, off);
        s2 += __shfl_down(s2, off);
    }
    __shared__ double sh1[TPB / 64], sh2[TPB / 64];
    int wv = threadIdx.x >> 6;
    if ((threadIdx.x & 63) == 0) { sh1[wv] = s1; sh2[wv] = s2; }
    __syncthreads();
    if (threadIdx.x == 0) {
        double t1 = 0.0, t2 = 0.0;
        for (int i = 0; i < TPB / 64; ++i) { t1 += sh1[i]; t2 += sh2[i]; }
        partial[((long long)c * NBX + blockIdx.x) * 2 + 0] = t1;
        partial[((long long)c * NBX + blockIdx.x) * 2 + 1] = t2;
    }
}

// ---------------- finalize: mean, rstd per channel ----------------
__global__ void k_finalize(const double* __restrict__ partial, double* __restrict__ mr,
                           int C, double cnt, int NBX) {
    int c = blockIdx.x * blockDim.x + threadIdx.x;
    if (c >= C) return;
    double s1 = 0.0, s2 = 0.0;
    for (int b = 0; b < NBX; ++b) {
        s1 += partial[((long long)c * NBX + b) * 2 + 0];
        s2 += partial[((long long)c * NBX + b) * 2 + 1];
    }
    double mean = s1 / cnt;
    double var = s2 / cnt - mean * mean;
    double rstd = 1.0 / sqrt(var + 1e-5);
    mr[2 * c + 0] = mean;
    mr[2 * c + 1] = rstd;
}

// ---------------- sign(bn(x)) -> int8 (div-free, vectorized) ----------------
template <typename T, int V>
__global__ void k_bnsign(const T* __restrict__ x, const double* __restrict__ mr,
                         const float* __restrict__ g, const float* __restrict__ b,
                         signed char* __restrict__ out, int C, int HW) {
    const int c = blockIdx.y;
    const int n = blockIdx.z;
    const double mean = mr[2 * c], rstd = mr[2 * c + 1];
    const double gg = (double)g[c], bb = (double)b[c];
    const T* xp = x + ((long long)n * C + c) * HW;
    signed char* op = out + ((long long)n * C + c) * HW;
    long long p = ((long long)blockIdx.x * TPB + threadIdx.x) * V;
    if (p + V > HW) {
        for (; p < HW; ++p) {
            double v = ((double)xp[p] - mean) * rstd * gg + bb;
            op[p] = v > 0.0 ? 1 : (v < 0.0 ? -1 : 0);
        }
        return;
    }
    T buf[V];
    __builtin_memcpy(buf, xp + p, V * sizeof(T));
    signed char o[V];
#pragma unroll
    for (int j = 0; j < V; ++j) {
        double v = ((double)buf[j] - mean) * rstd * gg + bb;
        o[j] = v > 0.0 ? 1 : (v < 0.0 ? -1 : 0);
    }
    __builtin_memcpy(op + p, o, V);
}

// ---------------- fused conv(int8 x int8, stride1, VALID) + 3x3 maxpool(stride S) ----------------
// Block: 256 thr; tx=tid&15 -> 4 consecutive conv cols, ty=tid>>4 -> 16 conv rows.
// One co0-phase (COT channels) per block; z = n*NPH + ph. CI in chunks of CIC.
// Input chunk in LDS (row stride 96B: 2-way bank aliasing = free).
// Weights in LDS laid out [ci][kh][co][NC] -> aligned ds_read_b128 broadcasts.
// NOTE: every access to acc[][] must be compile-time-indexed (full unroll), else
// the whole accumulator tile is scratch-allocated (rule #20) — this was the
// round-5..8 perf bug (VGPR_Count=36, scratch FETCH inflation).
template <int K, int COT, int S, int PH, int PW, int CIC>
__global__ __launch_bounds__(256, 4) void k_convpool(
    const signed char* __restrict__ a,   // [N][CI][H][W]
    const signed char* __restrict__ wp,  // [CO][CI][K][Kp] (dword rows)
    short* __restrict__ out,             // [N][CO][HOp][WOp]
    int CI, int H, int W, int CO, int HOp, int WOp, int NPH) {
    constexpr int Kp = (K + 3) & ~3;
    constexpr int NC = Kp / 4;
    constexpr int TH = 16 + K - 1;
    constexpr int TWB = 96, TWD = 24;    // LDS input row stride: bytes / dwords
    constexpr int WSTR = COT * NC;       // weight dwords per (ci,kh)
    extern __shared__ unsigned char lds[];
    unsigned char* in_t = lds;                                   // CIC*TH*TWB bytes
    unsigned int* w_t = (unsigned int*)(lds + CIC * TH * TWB);   // CIC*K*WSTR dwords
    short* pool_t = (short*)(lds + CIC * TH * TWB + CIC * K * WSTR * 4);  // [16][68]

    const int z = blockIdx.z;
    const int n = z / NPH;
    const int co0 = (z - n * NPH) * COT;
    const int p0 = blockIdx.y * PH;      // pool tile origin
    const int q0 = blockIdx.x * PW;
    const int oh0 = p0 * S;              // conv tile origin
    const int ow0 = q0 * S;              // 4-aligned by PW*S choice
    const int tid = threadIdx.x;
    const int tx = tid & 15, ty = tid >> 4;

    int acc[COT][4];
#pragma unroll
    for (int co = 0; co < COT; ++co)
#pragma unroll
        for (int j = 0; j < 4; ++j) acc[co][j] = 0;

    for (int ci0 = 0; ci0 < CI; ci0 += CIC) {
        __syncthreads();  // previous chunk's reads done before restaging
        // ---- stage input chunk (dword granularity, zero-fill OOB) ----
        for (int t = tid; t < CIC * TH * TWD; t += TPB) {
            int xd = t % TWD;
            int rest = t / TWD;
            int y = rest % TH;
            int ci = rest / TH;
            int gy = oh0 + y;
            int gx0 = ow0 + xd * 4;
            unsigned int v = 0;
            if (gy < H && gx0 < W) {
                const signed char* src =
                    a + ((long long)(n * CI + ci0 + ci) * H + gy) * W + gx0;
                if (gx0 + 3 < W) {
                    __builtin_memcpy(&v, src, 4);
                } else {
                    unsigned int b0 = (unsigned char)src[0], b1 = 0, b2 = 0;
                    if (gx0 + 1 < W) b1 = (unsigned char)src[1];
                    if (gx0 + 2 < W) b2 = (unsigned char)src[2];
                    v = b0 | (b1 << 8) | (b2 << 16);
                }
            }
            *(unsigned int*)&in_t[(ci * TH + y) * TWB + xd * 4] = v;
        }
        // ---- stage weight chunk, layout [ci][kh][co][NC] dwords ----
        constexpr int WTOT = CIC * K * WSTR;
        for (int t = tid; t < WTOT; t += TPB) {
            int c = t % NC;
            int rest = t / NC;
            int co = rest % COT;
            rest /= COT;
            int kh = rest % K;
            int ci = rest / K;
            w_t[t] = ((const unsigned int*)wp)[(((long long)(co0 + co) * CI + ci0 + ci) * K + kh) * NC + c];
        }
        __syncthreads();

        for (int ci = 0; ci < CIC; ++ci) {
#pragma unroll 1
            for (int kh = 0; kh < K; ++kh) {
                uint4 rr = *(const uint4*)&in_t[(ci * TH + ty + kh) * TWB + tx * 4];
                unsigned int r[4] = {rr.x, rr.y, rr.z, rr.w};
                // weights: aligned b128 broadcasts into registers
                unsigned int wreg[WSTR];
                const uint4* wsrc = (const uint4*)&w_t[(ci * K + kh) * WSTR];
#pragma unroll
                for (int i = 0; i < WSTR / 4; ++i) *(uint4*)&wreg[4 * i] = wsrc[i];
                unsigned int av[NC][4];
#pragma unroll
                for (int c = 0; c < NC; ++c) {
                    av[c][0] = r[c];
                    av[c][1] = alignb(r[c + 1], r[c], 1);
                    av[c][2] = alignb(r[c + 1], r[c], 2);
                    av[c][3] = alignb(r[c + 1], r[c], 3);
                }
#pragma unroll
                for (int co = 0; co < COT; ++co) {
#pragma unroll
                    for (int c = 0; c < NC; ++c) {
                        unsigned int w4 = wreg[co * NC + c];
                        acc[co][0] = dot4(av[c][0], w4, acc[co][0]);
                        acc[co][1] = dot4(av[c][1], w4, acc[co][1]);
                        acc[co][2] = dot4(av[c][2], w4, acc[co][2]);
                        acc[co][3] = dot4(av[c][3], w4, acc[co][3]);
                    }
                }
            }
        }
    }

    // ---- pool each of the COT channels through LDS ----
    // FULLY UNROLLED so acc[co] stays compile-time-indexed (register-resident).
#pragma unroll
    for (int co = 0; co < COT; ++co) {
        __syncthreads();  // previous co's pool reads done
        unsigned int lo = ((unsigned)acc[co][0] & 0xffffu) | ((unsigned)acc[co][1] << 16);
        unsigned int hi = ((unsigned)acc[co][2] & 0xffffu) | ((unsigned)acc[co][3] << 16);
        unsigned int* dst = (unsigned int*)&pool_t[ty * 68 + tx * 4];
        dst[0] = lo;
        dst[1] = hi;
        __syncthreads();
        constexpr int TOT = PH * PW;
#pragma unroll 1
        for (int t = tid; t < TOT; t += TPB) {
            int pp = t / PW, qq = t % PW;
            int p = p0 + pp, q = q0 + qq;
            if (p < HOp && q < WOp) {
                const short* pt = &pool_t[(S * pp) * 68 + S * qq];
                int m = pt[0];
                m = max(m, (int)pt[1]); m = max(m, (int)pt[2]);
                m = max(m, (int)pt[68]); m = max(m, (int)pt[69]); m = max(m, (int)pt[70]);
                m = max(m, (int)pt[136]); m = max(m, (int)pt[137]); m = max(m, (int)pt[138]);
                out[((long long)(n * CO + co0 + co) * HOp + p) * WOp + q] = (short)m;
            }
        }
    }
}

// ---------------- FC: [64,256] int8 @ [50,256]^T int8 -> float ----------------
__global__ void k_fc(const signed char* __restrict__ a, const signed char* __restrict__ w,
                     float* __restrict__ out) {
    int i = blockIdx.x * TPB + threadIdx.x;
    if (i >= 64 * 50) return;
    int n = i / 50, c = i % 50;
    int acc = 0;
    for (int k = 0; k < 256; ++k)
        acc += (int)a[n * 256 + k] * (int)w[c * 256 + k];
    out[i] = (float)acc;
}

static inline long long cdiv(long long a, long long b) { return (a + b - 1) / b; }

extern "C" void kernel_launch(void* const* d_in, const int* in_sizes, int n_in,
                              void* d_out, int out_size, void* d_ws, size_t ws_size,
                              hipStream_t stream) {
    const float* x = (const float*)d_in[0];
    const float* gs[7] = {(const float*)d_in[1], (const float*)d_in[4], (const float*)d_in[7],
                          (const float*)d_in[10], (const float*)d_in[13], (const float*)d_in[16],
                          (const float*)d_in[19]};
    const float* bs[7] = {(const float*)d_in[2], (const float*)d_in[5], (const float*)d_in[8],
                          (const float*)d_in[11], (const float*)d_in[14], (const float*)d_in[17],
                          (const float*)d_in[20]};
    const float* wsrc[7] = {(const float*)d_in[3], (const float*)d_in[6], (const float*)d_in[9],
                            (const float*)d_in[12], (const float*)d_in[15], (const float*)d_in[18],
                            (const float*)d_in[21]};

    // layer geometry
    const int C_[7] = {3, 8, 16, 32, 32, 64, 64};       // bn channels (input of layer L)
    const int Hin[7] = {224, 212, 102, 48, 21, 8, 2};   // spatial of bn input
    const int CO_[6] = {8, 16, 32, 32, 64, 64};
    const int K_[6] = {11, 7, 5, 5, 5, 3};
    const int KP_[6] = {12, 8, 8, 8, 8, 4};
    const int PS_[6] = {1, 2, 2, 2, 2, 2};
    const int PH_[6] = {14, 7, 7, 7, 7, 2};
    const int PW_[6] = {60, 30, 30, 30, 30, 2};
    const int CIC_[6] = {3, 8, 16, 16, 16, 16};
    const int N = 64;

    long long woff[7];
    {
        long long o = 0;
        for (int i = 0; i < 6; ++i) {
            woff[i] = o;
            o += (long long)CO_[i] * C_[i] * K_[i] * KP_[i];
            o = (o + 15) & ~15ll;
        }
        woff[6] = o;  // FC plain 50*256
    }

    // ---- workspace layout (~84 MB) ----
    char* ws = (char*)d_ws;
    double* partial = (double*)ws;                          // 256 KB
    double* mr = (double*)(ws + 262144);                    // 7*128 doubles
    signed char* wb = (signed char*)(ws + 278528);          // padded binarized weights (16B aligned)
    signed char* A = (signed char*)(ws + (1ll << 20));      // int8 activations, 24 MB slot
    short* Pb = (short*)(ws + (37ll << 20));                // pool out int16, 47 MB slot

    for (int i = 0; i < 6; ++i) {
        int total = CO_[i] * C_[i] * K_[i] * KP_[i];
        k_binwpad<<<dim3(cdiv(total, TPB)), TPB, 0, stream>>>(wsrc[i], wb + woff[i],
                                                              C_[i], K_[i], KP_[i], total);
    }
    k_binw<<<dim3(cdiv(50 * 256, TPB)), TPB, 0, stream>>>(wsrc[6], wb + woff[6], 50 * 256);

    const short* curP = nullptr;

    for (int L = 0; L < 7; ++L) {
        int C = C_[L], H = Hin[L], W = Hin[L];
        int HW = H * W;
        long long nhw = (long long)N * HW;
        double* mrl = mr + L * 128;
        const int V = (HW % 4 == 0) ? 4 : 1;
        int gsx = (int)min((long long)256, cdiv(HW, (long long)TPB * V));
        dim3 sg((unsigned)gsx, C);
        dim3 bg((unsigned)cdiv(HW, (long long)TPB * V), C, N);

        if (L == 0) {
            if (V == 4) {
                k_stats<float, 4><<<sg, TPB, 0, stream>>>(x, N, C, HW, partial, gsx);
                k_finalize<<<1, 64, 0, stream>>>(partial, mrl, C, (double)nhw, gsx);
                k_bnsign<float, 4><<<bg, TPB, 0, stream>>>(x, mrl, gs[L], bs[L], A, C, HW);
            } else {
                k_stats<float, 1><<<sg, TPB, 0, stream>>>(x, N, C, HW, partial, gsx);
                k_finalize<<<1, 64, 0, stream>>>(partial, mrl, C, (double)nhw, gsx);
                k_bnsign<float, 1><<<bg, TPB, 0, stream>>>(x, mrl, gs[L], bs[L], A, C, HW);
            }
        } else {
            if (V == 4) {
                k_stats<short, 4><<<sg, TPB, 0, stream>>>(curP, N, C, HW, partial, gsx);
                k_finalize<<<1, 64, 0, stream>>>(partial, mrl, C, (double)nhw, gsx);
                k_bnsign<short, 4><<<bg, TPB, 0, stream>>>(curP, mrl, gs[L], bs[L], A, C, HW);
            } else {
                k_stats<short, 1><<<sg, TPB, 0, stream>>>(curP, N, C, HW, partial, gsx);
                k_finalize<<<1, 64, 0, stream>>>(partial, mrl, C, (double)nhw, gsx);
                k_bnsign<short, 1><<<bg, TPB, 0, stream>>>(curP, mrl, gs[L], bs[L], A, C, HW);
            }
        }

        if (L == 6) {
            k_fc<<<dim3(cdiv(64 * 50, TPB)), TPB, 0, stream>>>(A, wb + woff[6], (float*)d_out);
            break;
        }

        int CO = CO_[L], K = K_[L];
        int HOc = H - K + 1;
        int s = PS_[L];
        int HOp = (HOc - 3) / s + 1, WOp = HOp;

        const int COT = 8;
        int NPH = CO / COT;
        dim3 cg((unsigned)cdiv(WOp, PW_[L]), (unsigned)cdiv(HOp, PH_[L]), (unsigned)(N * NPH));
        size_t lds = (size_t)CIC_[L] * (16 + K - 1) * 96 +
                     (size_t)CIC_[L] * K_[L] * 8 * KP_[L] + 16 * 68 * sizeof(short);
        switch (L) {
            case 0: k_convpool<11, 8, 1, 14, 60, 3><<<cg, TPB, lds, stream>>>(A, wb + woff[L], Pb, C, H, W, CO, HOp, WOp, NPH); break;
            case 1: k_convpool<7, 8, 2, 7, 30, 8><<<cg, TPB, lds, stream>>>(A, wb + woff[L], Pb, C, H, W, CO, HOp, WOp, NPH); break;
            case 2: k_convpool<5, 8, 2, 7, 30, 16><<<cg, TPB, lds, stream>>>(A, wb + woff[L], Pb, C, H, W, CO, HOp, WOp, NPH); break;
            case 3: k_convpool<5, 8, 2, 7, 30, 16><<<cg, TPB, lds, stream>>>(A, wb + woff[L], Pb, C, H, W, CO, HOp, WOp, NPH); break;
            case 4: k_convpool<5, 8, 2, 7, 30, 16><<<cg, TPB, lds, stream>>>(A, wb + woff[L], Pb, C, H, W, CO, HOp, WOp, NPH); break;
            case 5: k_convpool<3, 8, 2, 2, 2, 16><<<cg, TPB, lds, stream>>>(A, wb + woff[L], Pb, C, H, W, CO, HOp, WOp, NPH); break;
        }
        curP = Pb;
    }
}

// Round 10
// 763.129 us; speedup vs baseline: 17.2858x; 1.8182x over previous
//
#include <hip/hip_runtime.h>
#include <math.h>

#define TPB 256
typedef signed char schar;
typedef int v4i __attribute__((ext_vector_type(4)));

static inline long long cdiv(long long a, long long b) { return (a + b - 1) / b; }

// ---------------- weight binarize (plain, for FC) ----------------
__global__ void k_binw(const float* __restrict__ w, schar* __restrict__ wb, int n) {
    int i = blockIdx.x * TPB + threadIdx.x;
    if (i < n) {
        float v = w[i];
        wb[i] = v > 0.f ? 1 : (v < 0.f ? -1 : 0);
    }
}

// ---------------- repack conv weights into MFMA B-fragment order ----------------
// out[ct][kh][ks][lane][16B]: byte b of lane l = sign(W[co=ct*16+(l&15)][ci][kh][kw])
// where k = ks*64 + (l>>4)*16 + b, kw = k/CIp, ci = k%CIp; zero outside valid range.
__global__ void k_wfrag(const float* __restrict__ w, schar* __restrict__ out,
                        int CI, int CIp, int K, int KS, int CO, int total) {
    int i = blockIdx.x * TPB + threadIdx.x;
    if (i >= total) return;
    int b = i & 15;
    int l = (i >> 4) & 63;
    int rest = i >> 10;              // fragment index = ((ct*K + kh)*KS + ks)
    int ks = rest % KS; rest /= KS;
    int kh = rest % K;
    int ct = rest / K;
    int co = ct * 16 + (l & 15);
    int k = ks * 64 + ((l >> 4) << 4) + b;
    int kw = k / CIp;
    int ci = k - kw * CIp;
    schar v = 0;
    if (kw < K && ci < CI && co < CO) {
        float f = w[((co * CI + ci) * K + kh) * K + kw];
        v = f > 0.f ? 1 : (f < 0.f ? -1 : 0);
    }
    out[i] = v;
}

// ---------------- L0 stats: per-channel partial sum/sumsq over NCHW float ----------------
template <typename T, int V>
__global__ void k_stats(const T* __restrict__ x, int N, int C, int HW,
                        double* __restrict__ partial, int NBX) {
    int c = blockIdx.y;
    double s1 = 0.0, s2 = 0.0;
    const long long step = (long long)gridDim.x * TPB * V;
    for (int n = 0; n < N; ++n) {
        const T* xp = x + ((long long)n * C + c) * HW;
        for (long long p = ((long long)blockIdx.x * TPB + threadIdx.x) * V; p + V <= HW; p += step) {
            T buf[V];
            __builtin_memcpy(buf, xp + p, V * sizeof(T));
#pragma unroll
            for (int j = 0; j < V; ++j) {
                double v = (double)buf[j];
                s1 += v;
                s2 += v * v;
            }
        }
    }
    for (int off = 32; off > 0; off >>= 1) {
        s1 += __shfl_down(s1, off);
        s2 += __shfl_down(s2, off);
    }
    __shared__ double sh1[TPB / 64], sh2[TPB / 64];
    int wv = threadIdx.x >> 6;
    if ((threadIdx.x & 63) == 0) { sh1[wv] = s1; sh2[wv] = s2; }
    __syncthreads();
    if (threadIdx.x == 0) {
        double t1 = 0.0, t2 = 0.0;
        for (int i = 0; i < TPB / 64; ++i) { t1 += sh1[i]; t2 += sh2[i]; }
        partial[((long long)c * NBX + blockIdx.x) * 2 + 0] = t1;
        partial[((long long)c * NBX + blockIdx.x) * 2 + 1] = t2;
    }
}

// ---------------- finalize: mean, rstd per channel ----------------
__global__ void k_finalize(const double* __restrict__ partial, double* __restrict__ mr,
                           int C, double cnt, int NBX) {
    int c = blockIdx.x * blockDim.x + threadIdx.x;
    if (c >= C) return;
    double s1 = 0.0, s2 = 0.0;
    for (int b = 0; b < NBX; ++b) {
        s1 += partial[((long long)c * NBX + b) * 2 + 0];
        s2 += partial[((long long)c * NBX + b) * 2 + 1];
    }
    double mean = s1 / cnt;
    double var = s2 / cnt - mean * mean;
    double rstd = 1.0 / sqrt(var + 1e-5);
    mr[2 * c + 0] = mean;
    mr[2 * c + 1] = rstd;
}

// ---------------- NHWC int16 stats: grid (NBX, CO/8) ----------------
template <int CO>
__global__ void k_statsN(const short* __restrict__ x, long long P,
                         double* __restrict__ partial, int NBX) {
    const int ch = blockIdx.y;
    double s1[8], s2[8];
#pragma unroll
    for (int j = 0; j < 8; ++j) { s1[j] = 0.0; s2[j] = 0.0; }
    for (long long p = (long long)blockIdx.x * TPB + threadIdx.x; p < P; p += (long long)NBX * TPB) {
        short v[8];
        __builtin_memcpy(v, x + p * CO + ch * 8, 16);
#pragma unroll
        for (int j = 0; j < 8; ++j) { double d = (double)v[j]; s1[j] += d; s2[j] += d * d; }
    }
    for (int off = 32; off > 0; off >>= 1) {
#pragma unroll
        for (int j = 0; j < 8; ++j) {
            s1[j] += __shfl_down(s1[j], off);
            s2[j] += __shfl_down(s2[j], off);
        }
    }
    __shared__ double sh[4][16];
    int wv = threadIdx.x >> 6;
    if ((threadIdx.x & 63) == 0) {
#pragma unroll
        for (int j = 0; j < 8; ++j) { sh[wv][j] = s1[j]; sh[wv][8 + j] = s2[j]; }
    }
    __syncthreads();
    if (threadIdx.x == 0) {
        for (int j = 0; j < 8; ++j) {
            double t1 = 0.0, t2 = 0.0;
            for (int w2 = 0; w2 < 4; ++w2) { t1 += sh[w2][j]; t2 += sh[w2][8 + j]; }
            int co = ch * 8 + j;
            partial[((long long)co * NBX + blockIdx.x) * 2 + 0] = t1;
            partial[((long long)co * NBX + blockIdx.x) * 2 + 1] = t2;
        }
    }
}

// ---------------- NHWC int16 -> int8 sign(bn(x)): grid (pix blocks, CO/8) ----------------
template <int CO>
__global__ void k_bnsignN(const short* __restrict__ x, const double* __restrict__ mr,
                          const float* __restrict__ g, const float* __restrict__ b,
                          schar* __restrict__ out, long long P) {
    long long pix = (long long)blockIdx.x * TPB + threadIdx.x;
    if (pix >= P) return;
    const int ch = blockIdx.y;
    short v[8];
    __builtin_memcpy(v, x + pix * CO + ch * 8, 16);
    schar o[8];
#pragma unroll
    for (int j = 0; j < 8; ++j) {
        int co = ch * 8 + j;
        double d = ((double)v[j] - mr[2 * co]) * mr[2 * co + 1] * (double)g[co] + (double)b[co];
        o[j] = d > 0.0 ? 1 : (d < 0.0 ? -1 : 0);
    }
    __builtin_memcpy(out + pix * CO + ch * 8, o, 8);
}

// ---------------- L0: NCHW float -> NHWC(CIp=4) int8 signs ----------------
__global__ void k_bnsign0(const float* __restrict__ x, const double* __restrict__ mr,
                          const float* __restrict__ g, const float* __restrict__ b,
                          schar* __restrict__ A) {
    int id = blockIdx.x * TPB + threadIdx.x;
    if (id >= 64 * 224 * 224) return;
    int xw = id % 224;
    int t = id / 224;
    int y = t % 224;
    int n = t / 224;
    unsigned o = 0;
    for (int c = 0; c < 3; ++c) {
        double v = ((double)x[(((long long)(n * 3 + c)) * 224 + y) * 224 + xw] - mr[2 * c]) *
                       mr[2 * c + 1] * (double)g[c] + (double)b[c];
        schar s = v > 0.0 ? 1 : (v < 0.0 ? -1 : 0);
        o |= ((unsigned)(unsigned char)s) << (8 * c);
    }
    ((unsigned*)A)[id] = o;
}

// ---------------- MFMA implicit-GEMM conv, NHWC int8 -> NHWC int16 ----------------
// 4 waves/block, one 16-pixel M-tile per wave. Per (kh,ks): A = contiguous 16B of
// NHWC memory (im2col over (kw,ci) is contiguous); B = prepacked fragment (1KB,
// coalesced). D layout: col=co=lane&15, row=pixel=(lane>>4)*4+reg (m89-verified).
template <int CIp, int K, int KS, int CT, int H, int W, int HO, int WO, int CO>
__global__ __launch_bounds__(256) void k_convmf(const schar* __restrict__ a,
                                                const schar* __restrict__ wf,
                                                short* __restrict__ cout, int npix) {
    const int tid = threadIdx.x;
    const int wave = tid >> 6, lane = tid & 63;
    const int pid0 = (blockIdx.x * 4 + wave) * 16;
    int pA = pid0 + (lane & 15);
    if (pA >= npix) pA = npix - 1;
    const int ow = pA % WO;
    int t = pA / WO;
    const int oh = t % HO;
    const int n = t / HO;
    const schar* abase = a + (long long)((n * H + oh) * W + ow) * CIp + ((lane >> 4) << 4);

    v4i acc[CT];
#pragma unroll
    for (int ct = 0; ct < CT; ++ct) acc[ct] = (v4i){0, 0, 0, 0};

#pragma unroll
    for (int kh = 0; kh < K; ++kh) {
        const schar* arow = abase + kh * W * CIp;
#pragma unroll
        for (int ks = 0; ks < KS; ++ks) {
            v4i av;
            __builtin_memcpy(&av, arow + ks * 64, 16);
#pragma unroll
            for (int ct = 0; ct < CT; ++ct) {
                v4i bv;
                __builtin_memcpy(&bv, wf + (long long)((((ct * K + kh) * KS + ks) << 6) + lane) * 16, 16);
                acc[ct] = __builtin_amdgcn_mfma_i32_16x16x64_i8(av, bv, acc[ct], 0, 0, 0);
            }
        }
    }

    // transpose D to NHWC int16 via per-wave LDS tile, then wide coalesced stores
    __shared__ __align__(16) short lt[4][16][CO];
#pragma unroll
    for (int ct = 0; ct < CT; ++ct) {
        int co = ct * 16 + (lane & 15);
        if (CO >= 16 || co < CO) {
#pragma unroll
            for (int r = 0; r < 4; ++r)
                lt[wave][((lane >> 4) << 2) + r][co] = (short)acc[ct][r];
        }
    }
    __syncthreads();
    constexpr int BPL = CO / 2;  // bytes per lane (4/8/16/32)
    const int pix = pid0 + (lane >> 2);
    if (pix < npix) {
        const char* src = (const char*)&lt[wave][0][0] + lane * BPL;
        char* dst = (char*)cout + (long long)pix * CO * 2 + (lane & 3) * BPL;
        if constexpr (BPL == 4) {
            unsigned v; __builtin_memcpy(&v, src, 4); __builtin_memcpy(dst, &v, 4);
        } else if constexpr (BPL == 8) {
            uint2 v; __builtin_memcpy(&v, src, 8); __builtin_memcpy(dst, &v, 8);
        } else if constexpr (BPL == 16) {
            uint4 v; __builtin_memcpy(&v, src, 16); __builtin_memcpy(dst, &v, 16);
        } else {
            uint4 v0, v1;
            __builtin_memcpy(&v0, src, 16); __builtin_memcpy(&v1, src + 16, 16);
            __builtin_memcpy(dst, &v0, 16); __builtin_memcpy(dst + 16, &v1, 16);
        }
    }
}

// ---------------- NHWC 3x3 maxpool stride S: grid (pix blocks, CO/8) ----------------
template <int HOc, int CO, int S, int HOp>
__global__ void k_poolN(const short* __restrict__ in, short* __restrict__ out, int npox) {
    int pox = blockIdx.x * TPB + threadIdx.x;
    if (pox >= npox) return;
    const int ch = blockIdx.y;
    const int q = pox % HOp;
    int t = pox / HOp;
    const int p = t % HOp;
    const int n = t / HOp;
    const short* base = in + (long long)((n * HOc + p * S) * HOc + q * S) * CO + ch * 8;
    short m[8];
#pragma unroll
    for (int j = 0; j < 8; ++j) m[j] = -32768;
#pragma unroll
    for (int dy = 0; dy < 3; ++dy) {
#pragma unroll
        for (int dx = 0; dx < 3; ++dx) {
            short v[8];
            __builtin_memcpy(v, base + (dy * HOc + dx) * CO, 16);
#pragma unroll
            for (int j = 0; j < 8; ++j) m[j] = v[j] > m[j] ? v[j] : m[j];
        }
    }
    __builtin_memcpy(out + (long long)((n * HOp + p) * HOp + q) * CO + ch * 8, m, 16);
}

// ---------------- FC: NHWC [64][2][2][64] int8 @ sign(wfc)^T -> float [64][50] ----------------
__global__ void k_fc(const schar* __restrict__ a, const schar* __restrict__ w,
                     float* __restrict__ out) {
    int i = blockIdx.x * TPB + threadIdx.x;
    if (i >= 64 * 50) return;
    int n = i / 50, cls = i % 50;
    int acc = 0;
    for (int k = 0; k < 256; ++k) {
        int c = k >> 2, pos = k & 3;  // ref flatten (NCHW): k = c*4 + (y*2+x)
        acc += (int)a[(n * 4 + pos) * 64 + c] * (int)w[cls * 256 + k];
    }
    out[i] = (float)acc;
}

extern "C" void kernel_launch(void* const* d_in, const int* in_sizes, int n_in,
                              void* d_out, int out_size, void* d_ws, size_t ws_size,
                              hipStream_t stream) {
    const float* x = (const float*)d_in[0];
    const float* gs[7] = {(const float*)d_in[1], (const float*)d_in[4], (const float*)d_in[7],
                          (const float*)d_in[10], (const float*)d_in[13], (const float*)d_in[16],
                          (const float*)d_in[19]};
    const float* bs[7] = {(const float*)d_in[2], (const float*)d_in[5], (const float*)d_in[8],
                          (const float*)d_in[11], (const float*)d_in[14], (const float*)d_in[17],
                          (const float*)d_in[20]};
    const float* wsrc[7] = {(const float*)d_in[3], (const float*)d_in[6], (const float*)d_in[9],
                            (const float*)d_in[12], (const float*)d_in[15], (const float*)d_in[18],
                            (const float*)d_in[21]};

    // per-layer conv geometry
    const int CI_[6] = {3, 8, 16, 32, 32, 64};
    const int CIp_[6] = {4, 8, 16, 32, 32, 64};
    const int K_[6] = {11, 7, 5, 5, 5, 3};
    const int KS_[6] = {1, 1, 2, 3, 3, 3};
    const int CO_[6] = {8, 16, 32, 32, 64, 64};
    const int CT_[6] = {1, 1, 2, 2, 4, 4};

    // fragment buffer offsets (bytes): size = CT*K*KS*1024
    long long foff[6];
    {
        long long o = 0;
        for (int i = 0; i < 6; ++i) {
            foff[i] = o;
            o += (long long)CT_[i] * K_[i] * KS_[i] * 1024;
        }
    }

    // ---- workspace layout (~95 MB; round-1 evidence shows ws >= ~112 MB) ----
    char* ws = (char*)d_ws;
    double* partial = (double*)ws;                    // 256 KB  [co][NBX][2]
    double* mr = (double*)(ws + 262144);              // 7*128 doubles
    schar* wfrag = (schar*)(ws + 524288);             // ~168 KB fragments
    schar* wbfc = (schar*)(ws + 786432);              // 12.8 KB FC signs
    schar* A = (schar*)(ws + (1ll << 20));            // NHWC int8 acts, 25 MB slot (+guard)
    short* C = (short*)(ws + (26ll << 20));           // NHWC int16 conv out, 23 MB slot
    short* P = (short*)(ws + (49ll << 20));           // NHWC int16 pool out, 46.2 MB slot

    // ---- weight repacks ----
    for (int i = 0; i < 6; ++i) {
        int total = CT_[i] * K_[i] * KS_[i] * 1024;
        k_wfrag<<<dim3(cdiv(total, TPB)), TPB, 0, stream>>>(wsrc[i], wfrag + foff[i],
                                                            CI_[i], CIp_[i], K_[i], KS_[i],
                                                            CO_[i], total);
    }
    k_binw<<<dim3(cdiv(50 * 256, TPB)), TPB, 0, stream>>>(wsrc[6], wbfc, 50 * 256);

    const int NBX = 128;

    // ================= L0: bn(x) -> sign -> NHWC4; conv 11x11; pool s1 =================
    {
        int gsx = (int)min((long long)256, cdiv(224 * 224, (long long)TPB * 4));
        k_stats<float, 4><<<dim3(gsx, 3), TPB, 0, stream>>>(x, 64, 3, 224 * 224, partial, gsx);
        k_finalize<<<1, 64, 0, stream>>>(partial, mr, 3, 64.0 * 224 * 224, gsx);
        k_bnsign0<<<dim3(cdiv(64 * 224 * 224, TPB)), TPB, 0, stream>>>(x, mr, gs[0], bs[0], A);
        for (int n0 = 0; n0 < 64; n0 += 16) {
            int npix = 16 * 214 * 214;
            k_convmf<4, 11, 1, 1, 224, 224, 214, 214, 8>
                <<<dim3(cdiv(npix, 64)), TPB, 0, stream>>>(A + (long long)n0 * 224 * 224 * 4,
                                                           wfrag + foff[0], C, npix);
            int npox = 16 * 212 * 212;
            k_poolN<214, 8, 1, 212><<<dim3(cdiv(npox, TPB), 1), TPB, 0, stream>>>(
                C, P + (long long)n0 * 212 * 212 * 8, npox);
        }
    }
    // ================= L1: bn -> sign NHWC8; conv 7x7; pool s2 =================
    {
        long long Pcnt = 64ll * 212 * 212;
        k_statsN<8><<<dim3(NBX, 1), TPB, 0, stream>>>(P, Pcnt, partial, NBX);
        k_finalize<<<1, 64, 0, stream>>>(partial, mr + 128, 8, (double)Pcnt, NBX);
        k_bnsignN<8><<<dim3(cdiv(Pcnt, TPB), 1), TPB, 0, stream>>>(P, mr + 128, gs[1], bs[1], A, Pcnt);
        for (int n0 = 0; n0 < 64; n0 += 16) {
            int npix = 16 * 206 * 206;
            k_convmf<8, 7, 1, 1, 212, 212, 206, 206, 16>
                <<<dim3(cdiv(npix, 64)), TPB, 0, stream>>>(A + (long long)n0 * 212 * 212 * 8,
                                                           wfrag + foff[1], C, npix);
            int npox = 16 * 102 * 102;
            k_poolN<206, 16, 2, 102><<<dim3(cdiv(npox, TPB), 2), TPB, 0, stream>>>(
                C, P + (long long)n0 * 102 * 102 * 16, npox);
        }
    }
    // ================= L2: bn -> sign NHWC16; conv 5x5; pool s2 =================
    {
        long long Pcnt = 64ll * 102 * 102;
        k_statsN<16><<<dim3(NBX, 2), TPB, 0, stream>>>(P, Pcnt, partial, NBX);
        k_finalize<<<1, 64, 0, stream>>>(partial, mr + 256, 16, (double)Pcnt, NBX);
        k_bnsignN<16><<<dim3(cdiv(Pcnt, TPB), 2), TPB, 0, stream>>>(P, mr + 256, gs[2], bs[2], A, Pcnt);
        for (int n0 = 0; n0 < 64; n0 += 32) {
            int npix = 32 * 98 * 98;
            k_convmf<16, 5, 2, 2, 102, 102, 98, 98, 32>
                <<<dim3(cdiv(npix, 64)), TPB, 0, stream>>>(A + (long long)n0 * 102 * 102 * 16,
                                                           wfrag + foff[2], C, npix);
            int npox = 32 * 48 * 48;
            k_poolN<98, 32, 2, 48><<<dim3(cdiv(npox, TPB), 4), TPB, 0, stream>>>(
                C, P + (long long)n0 * 48 * 48 * 32, npox);
        }
    }
    // ================= L3: conv 5x5 CI32->CO32; pool s2 =================
    {
        long long Pcnt = 64ll * 48 * 48;
        k_statsN<32><<<dim3(NBX, 4), TPB, 0, stream>>>(P, Pcnt, partial, NBX);
        k_finalize<<<1, 64, 0, stream>>>(partial, mr + 384, 32, (double)Pcnt, NBX);
        k_bnsignN<32><<<dim3(cdiv(Pcnt, TPB), 4), TPB, 0, stream>>>(P, mr + 384, gs[3], bs[3], A, Pcnt);
        int npix = 64 * 44 * 44;
        k_convmf<32, 5, 3, 2, 48, 48, 44, 44, 32>
            <<<dim3(cdiv(npix, 64)), TPB, 0, stream>>>(A, wfrag + foff[3], C, npix);
        int npox = 64 * 21 * 21;
        k_poolN<44, 32, 2, 21><<<dim3(cdiv(npox, TPB), 4), TPB, 0, stream>>>(C, P, npox);
    }
    // ================= L4: conv 5x5 CI32->CO64; pool s2 =================
    {
        long long Pcnt = 64ll * 21 * 21;
        k_statsN<32><<<dim3(NBX, 4), TPB, 0, stream>>>(P, Pcnt, partial, NBX);
        k_finalize<<<1, 64, 0, stream>>>(partial, mr + 512, 32, (double)Pcnt, NBX);
        k_bnsignN<32><<<dim3(cdiv(Pcnt, TPB), 4), TPB, 0, stream>>>(P, mr + 512, gs[4], bs[4], A, Pcnt);
        int npix = 64 * 17 * 17;
        k_convmf<32, 5, 3, 4, 21, 21, 17, 17, 64>
            <<<dim3(cdiv(npix, 64)), TPB, 0, stream>>>(A, wfrag + foff[4], C, npix);
        int npox = 64 * 8 * 8;
        k_poolN<17, 64, 2, 8><<<dim3(cdiv(npox, TPB), 8), TPB, 0, stream>>>(C, P, npox);
    }
    // ================= L5: conv 3x3 CI64->CO64; pool s2 =================
    {
        long long Pcnt = 64ll * 8 * 8;
        k_statsN<64><<<dim3(NBX, 8), TPB, 0, stream>>>(P, Pcnt, partial, NBX);
        k_finalize<<<1, 64, 0, stream>>>(partial, mr + 640, 64, (double)Pcnt, NBX);
        k_bnsignN<64><<<dim3(cdiv(Pcnt, TPB), 8), TPB, 0, stream>>>(P, mr + 640, gs[5], bs[5], A, Pcnt);
        int npix = 64 * 6 * 6;
        k_convmf<64, 3, 3, 4, 8, 8, 6, 6, 64>
            <<<dim3(cdiv(npix, 64)), TPB, 0, stream>>>(A, wfrag + foff[5], C, npix);
        int npox = 64 * 2 * 2;
        k_poolN<6, 64, 2, 2><<<dim3(cdiv(npox, TPB), 8), TPB, 0, stream>>>(C, P, npox);
    }
    // ================= L6: bn -> sign; FC =================
    {
        long long Pcnt = 64ll * 2 * 2;
        k_statsN<64><<<dim3(NBX, 8), TPB, 0, stream>>>(P, Pcnt, partial, NBX);
        k_finalize<<<1, 64, 0, stream>>>(partial, mr + 768, 64, (double)Pcnt, NBX);
        k_bnsignN<64><<<dim3(cdiv(Pcnt, TPB), 8), TPB, 0, stream>>>(P, mr + 768, gs[6], bs[6], A, Pcnt);
        k_fc<<<dim3(cdiv(64 * 50, TPB)), TPB, 0, stream>>>(A, wbfc, (float*)d_out);
    }
}

// Round 11
// 608.410 us; speedup vs baseline: 21.6816x; 1.2543x over previous
//
#include <hip/hip_runtime.h>
#include <math.h>

#define TPB 256
typedef signed char schar;
typedef int v4i __attribute__((ext_vector_type(4)));

static inline long long cdiv(long long a, long long b) { return (a + b - 1) / b; }

// ---------------- weight binarize (plain, for FC) ----------------
__global__ void k_binw(const float* __restrict__ w, schar* __restrict__ wb, int n) {
    int i = blockIdx.x * TPB + threadIdx.x;
    if (i < n) {
        float v = w[i];
        wb[i] = v > 0.f ? 1 : (v < 0.f ? -1 : 0);
    }
}

// ---------------- repack conv weights into MFMA B-fragment order ----------------
// out[ct][kh][ks][lane][16B]: byte b of lane l = sign(W[co=ct*16+(l&15)][ci][kh][kw])
// where k = ks*64 + (l>>4)*16 + b, kw = k/CIp, ci = k%CIp; zero outside valid range.
__global__ void k_wfrag(const float* __restrict__ w, schar* __restrict__ out,
                        int CI, int CIp, int K, int KS, int CO, int total) {
    int i = blockIdx.x * TPB + threadIdx.x;
    if (i >= total) return;
    int b = i & 15;
    int l = (i >> 4) & 63;
    int rest = i >> 10;              // fragment index = ((ct*K + kh)*KS + ks)
    int ks = rest % KS; rest /= KS;
    int kh = rest % K;
    int ct = rest / K;
    int co = ct * 16 + (l & 15);
    int k = ks * 64 + ((l >> 4) << 4) + b;
    int kw = k / CIp;
    int ci = k - kw * CIp;
    schar v = 0;
    if (kw < K && ci < CI && co < CO) {
        float f = w[((co * CI + ci) * K + kh) * K + kw];
        v = f > 0.f ? 1 : (f < 0.f ? -1 : 0);
    }
    out[i] = v;
}

// ---------------- L0 stats: per-channel partial sum/sumsq over NCHW float ----------------
template <typename T, int V>
__global__ void k_stats(const T* __restrict__ x, int N, int C, int HW,
                        double* __restrict__ partial, int NBX) {
    int c = blockIdx.y;
    double s1 = 0.0, s2 = 0.0;
    const long long step = (long long)gridDim.x * TPB * V;
    for (int n = 0; n < N; ++n) {
        const T* xp = x + ((long long)n * C + c) * HW;
        for (long long p = ((long long)blockIdx.x * TPB + threadIdx.x) * V; p + V <= HW; p += step) {
            T buf[V];
            __builtin_memcpy(buf, xp + p, V * sizeof(T));
#pragma unroll
            for (int j = 0; j < V; ++j) {
                double v = (double)buf[j];
                s1 += v;
                s2 += v * v;
            }
        }
    }
    for (int off = 32; off > 0; off >>= 1) {
        s1 += __shfl_down(s1, off);
        s2 += __shfl_down(s2, off);
    }
    __shared__ double sh1[TPB / 64], sh2[TPB / 64];
    int wv = threadIdx.x >> 6;
    if ((threadIdx.x & 63) == 0) { sh1[wv] = s1; sh2[wv] = s2; }
    __syncthreads();
    if (threadIdx.x == 0) {
        double t1 = 0.0, t2 = 0.0;
        for (int i = 0; i < TPB / 64; ++i) { t1 += sh1[i]; t2 += sh2[i]; }
        partial[((long long)c * NBX + blockIdx.x) * 2 + 0] = t1;
        partial[((long long)c * NBX + blockIdx.x) * 2 + 1] = t2;
    }
}

// ---------------- finalize: mean, rstd per channel ----------------
__global__ void k_finalize(const double* __restrict__ partial, double* __restrict__ mr,
                           int C, double cnt, int NBX) {
    int c = blockIdx.x * blockDim.x + threadIdx.x;
    if (c >= C) return;
    double s1 = 0.0, s2 = 0.0;
    for (int b = 0; b < NBX; ++b) {
        s1 += partial[((long long)c * NBX + b) * 2 + 0];
        s2 += partial[((long long)c * NBX + b) * 2 + 1];
    }
    double mean = s1 / cnt;
    double var = s2 / cnt - mean * mean;
    double rstd = 1.0 / sqrt(var + 1e-5);
    mr[2 * c + 0] = mean;
    mr[2 * c + 1] = rstd;
}

// ---------------- NHWC int16 stats: grid (NBX, CO/8) ----------------
template <int CO>
__global__ void k_statsN(const short* __restrict__ x, long long P,
                         double* __restrict__ partial, int NBX) {
    const int ch = blockIdx.y;
    double s1[8], s2[8];
#pragma unroll
    for (int j = 0; j < 8; ++j) { s1[j] = 0.0; s2[j] = 0.0; }
    for (long long p = (long long)blockIdx.x * TPB + threadIdx.x; p < P; p += (long long)NBX * TPB) {
        short v[8];
        __builtin_memcpy(v, x + p * CO + ch * 8, 16);
#pragma unroll
        for (int j = 0; j < 8; ++j) { double d = (double)v[j]; s1[j] += d; s2[j] += d * d; }
    }
    for (int off = 32; off > 0; off >>= 1) {
#pragma unroll
        for (int j = 0; j < 8; ++j) {
            s1[j] += __shfl_down(s1[j], off);
            s2[j] += __shfl_down(s2[j], off);
        }
    }
    __shared__ double sh[4][16];
    int wv = threadIdx.x >> 6;
    if ((threadIdx.x & 63) == 0) {
#pragma unroll
        for (int j = 0; j < 8; ++j) { sh[wv][j] = s1[j]; sh[wv][8 + j] = s2[j]; }
    }
    __syncthreads();
    if (threadIdx.x == 0) {
        for (int j = 0; j < 8; ++j) {
            double t1 = 0.0, t2 = 0.0;
            for (int w2 = 0; w2 < 4; ++w2) { t1 += sh[w2][j]; t2 += sh[w2][8 + j]; }
            int co = ch * 8 + j;
            partial[((long long)co * NBX + blockIdx.x) * 2 + 0] = t1;
            partial[((long long)co * NBX + blockIdx.x) * 2 + 1] = t2;
        }
    }
}

// ---------------- NHWC int16 -> int8 sign(bn(x)): grid (pix blocks, CO/8) ----------------
template <int CO>
__global__ void k_bnsignN(const short* __restrict__ x, const double* __restrict__ mr,
                          const float* __restrict__ g, const float* __restrict__ b,
                          schar* __restrict__ out, long long P) {
    long long pix = (long long)blockIdx.x * TPB + threadIdx.x;
    if (pix >= P) return;
    const int ch = blockIdx.y;
    short v[8];
    __builtin_memcpy(v, x + pix * CO + ch * 8, 16);
    schar o[8];
#pragma unroll
    for (int j = 0; j < 8; ++j) {
        int co = ch * 8 + j;
        double d = ((double)v[j] - mr[2 * co]) * mr[2 * co + 1] * (double)g[co] + (double)b[co];
        o[j] = d > 0.0 ? 1 : (d < 0.0 ? -1 : 0);
    }
    __builtin_memcpy(out + pix * CO + ch * 8, o, 8);
}

// ---------------- L0: NCHW float -> NHWC(CIp=4) int8 signs ----------------
__global__ void k_bnsign0(const float* __restrict__ x, const double* __restrict__ mr,
                          const float* __restrict__ g, const float* __restrict__ b,
                          schar* __restrict__ A) {
    int id = blockIdx.x * TPB + threadIdx.x;
    if (id >= 64 * 224 * 224) return;
    int xw = id % 224;
    int t = id / 224;
    int y = t % 224;
    int n = t / 224;
    unsigned o = 0;
    for (int c = 0; c < 3; ++c) {
        double v = ((double)x[(((long long)(n * 3 + c)) * 224 + y) * 224 + xw] - mr[2 * c]) *
                       mr[2 * c + 1] * (double)g[c] + (double)b[c];
        schar s = v > 0.0 ? 1 : (v < 0.0 ? -1 : 0);
        o |= ((unsigned)(unsigned char)s) << (8 * c);
    }
    ((unsigned*)A)[id] = o;
}

// ---------------- fused MFMA implicit-GEMM conv + 3x3/S maxpool, NHWC ----------------
// Block: 4 waves, one image (blockIdx.y), PH pooled rows (blockIdx.x). Waves compute
// CR = PH*S+3-S conv rows x WOc cols into LDS [CR][WOc][CO] int16, then pool from LDS
// and write P directly (no conv-out buffer). A-frag: lane&15=pixel (per-lane gather),
// (lane>>4)*16=k-bytes. D: co=lane&15, pixel=(lane>>4)*4+reg (verified rounds 10).
template <int CIp, int K, int KS, int CT, int CO, int S, int PH, int H, int W>
__global__ __launch_bounds__(256) void k_convpoolmf(
    const schar* __restrict__ a, const schar* __restrict__ wf, short* __restrict__ pout) {
    constexpr int HOc = H - K + 1, WOc = W - K + 1;
    constexpr int HOp = (HOc - 3) / S + 1, WOp = (WOc - 3) / S + 1;
    constexpr int CR = PH * S + 3 - S;
    constexpr int NPIX = CR * WOc;
    constexpr int NTILE = (NPIX + 15) / 16;
    __shared__ __align__(16) short lt[CR][WOc][CO];

    const int tid = threadIdx.x, wave = tid >> 6, lane = tid & 63;
    const int n = blockIdx.y;
    const int p0 = blockIdx.x * PH;   // first pooled row
    const int r0 = p0 * S;            // first conv row

    for (int tile = wave; tile < NTILE; tile += 4) {
        const int pa = tile * 16 + (lane & 15);
        int r = pa / WOc, c = pa - r * WOc;
        if (pa >= NPIX || r0 + r >= HOc) { r = 0; c = 0; }  // clamp (r0 < HOc always)
        const schar* abase = a + (long long)((n * H + r0 + r) * W + c) * CIp + ((lane >> 4) << 4);

        v4i acc[CT];
#pragma unroll
        for (int ct = 0; ct < CT; ++ct) acc[ct] = (v4i){0, 0, 0, 0};
#pragma unroll
        for (int kh = 0; kh < K; ++kh) {
            const schar* arow = abase + kh * W * CIp;
#pragma unroll
            for (int ks = 0; ks < KS; ++ks) {
                v4i av;
                __builtin_memcpy(&av, arow + ks * 64, 16);
#pragma unroll
                for (int ct = 0; ct < CT; ++ct) {
                    v4i bv;
                    __builtin_memcpy(&bv, wf + (long long)((((ct * K + kh) * KS + ks) << 6) + lane) * 16, 16);
                    acc[ct] = __builtin_amdgcn_mfma_i32_16x16x64_i8(av, bv, acc[ct], 0, 0, 0);
                }
            }
        }
        // scatter D to LDS tile
#pragma unroll
        for (int ct = 0; ct < CT; ++ct) {
            const int co = ct * 16 + (lane & 15);
#pragma unroll
            for (int rg = 0; rg < 4; ++rg) {
                const int pd = tile * 16 + ((lane >> 4) << 2) + rg;
                const int rd = pd / WOc, cd = pd - rd * WOc;
                if (pd < NPIX && r0 + rd < HOc && (CO >= 16 || co < CO))
                    lt[rd][cd][co] = (short)acc[ct][rg];
            }
        }
    }
    __syncthreads();

    // pool from LDS, write NHWC int16
    constexpr int CG = CO / 8;
    const int chg = tid & (CG - 1);
    for (int o = tid / CG; o < PH * WOp; o += TPB / CG) {
        const int q = o % WOp, pp = o / WOp;
        const int p = p0 + pp;
        if (p >= HOp) break;
        short m[8];
#pragma unroll
        for (int j = 0; j < 8; ++j) m[j] = -32768;
#pragma unroll
        for (int dy = 0; dy < 3; ++dy)
#pragma unroll
            for (int dx = 0; dx < 3; ++dx) {
                short v[8];
                __builtin_memcpy(v, &lt[S * pp + dy][S * q + dx][chg * 8], 16);
#pragma unroll
                for (int j = 0; j < 8; ++j) m[j] = v[j] > m[j] ? v[j] : m[j];
            }
        __builtin_memcpy(pout + ((long long)(n * HOp + p) * WOp + q) * CO + chg * 8, m, 16);
    }
}

// ---------------- FC: NHWC [64][2][2][64] int8 @ sign(wfc)^T -> float [64][50] ----------------
__global__ void k_fc(const schar* __restrict__ a, const schar* __restrict__ w,
                     float* __restrict__ out) {
    int i = blockIdx.x * TPB + threadIdx.x;
    if (i >= 64 * 50) return;
    int n = i / 50, cls = i % 50;
    int acc = 0;
    for (int k = 0; k < 256; ++k) {
        int c = k >> 2, pos = k & 3;  // ref flatten (NCHW): k = c*4 + (y*2+x)
        acc += (int)a[(n * 4 + pos) * 64 + c] * (int)w[cls * 256 + k];
    }
    out[i] = (float)acc;
}

extern "C" void kernel_launch(void* const* d_in, const int* in_sizes, int n_in,
                              void* d_out, int out_size, void* d_ws, size_t ws_size,
                              hipStream_t stream) {
    const float* x = (const float*)d_in[0];
    const float* gs[7] = {(const float*)d_in[1], (const float*)d_in[4], (const float*)d_in[7],
                          (const float*)d_in[10], (const float*)d_in[13], (const float*)d_in[16],
                          (const float*)d_in[19]};
    const float* bs[7] = {(const float*)d_in[2], (const float*)d_in[5], (const float*)d_in[8],
                          (const float*)d_in[11], (const float*)d_in[14], (const float*)d_in[17],
                          (const float*)d_in[20]};
    const float* wsrc[7] = {(const float*)d_in[3], (const float*)d_in[6], (const float*)d_in[9],
                            (const float*)d_in[12], (const float*)d_in[15], (const float*)d_in[18],
                            (const float*)d_in[21]};

    // per-layer conv geometry
    const int CI_[6] = {3, 8, 16, 32, 32, 64};
    const int CIp_[6] = {4, 8, 16, 32, 32, 64};
    const int K_[6] = {11, 7, 5, 5, 5, 3};
    const int KS_[6] = {1, 1, 2, 3, 3, 3};
    const int CO_[6] = {8, 16, 32, 32, 64, 64};
    const int CT_[6] = {1, 1, 2, 2, 4, 4};

    long long foff[6];
    {
        long long o = 0;
        for (int i = 0; i < 6; ++i) {
            foff[i] = o;
            o += (long long)CT_[i] * K_[i] * KS_[i] * 1024;
        }
    }

    // ---- workspace layout (~72 MB) ----
    char* ws = (char*)d_ws;
    double* partial = (double*)ws;                    // 256 KB  [co][NBX][2]
    double* mr = (double*)(ws + 262144);              // 7*128 doubles
    schar* wfrag = (schar*)(ws + 524288);             // ~168 KB fragments
    schar* wbfc = (schar*)(ws + 786432);              // 12.8 KB FC signs
    schar* A = (schar*)(ws + (1ll << 20));            // NHWC int8 acts, 25 MB slot
    short* P = (short*)(ws + (26ll << 20));           // NHWC int16 pool out, 46.2 MB slot

    // ---- weight repacks ----
    for (int i = 0; i < 6; ++i) {
        int total = CT_[i] * K_[i] * KS_[i] * 1024;
        k_wfrag<<<dim3(cdiv(total, TPB)), TPB, 0, stream>>>(wsrc[i], wfrag + foff[i],
                                                            CI_[i], CIp_[i], K_[i], KS_[i],
                                                            CO_[i], total);
    }
    k_binw<<<dim3(cdiv(50 * 256, TPB)), TPB, 0, stream>>>(wsrc[6], wbfc, 50 * 256);

    const int NBX = 128;

    // ================= L0 =================
    {
        int gsx = (int)min((long long)256, cdiv(224 * 224, (long long)TPB * 4));
        k_stats<float, 4><<<dim3(gsx, 3), TPB, 0, stream>>>(x, 64, 3, 224 * 224, partial, gsx);
        k_finalize<<<1, 64, 0, stream>>>(partial, mr, 3, 64.0 * 224 * 224, gsx);
        k_bnsign0<<<dim3(cdiv(64 * 224 * 224, TPB)), TPB, 0, stream>>>(x, mr, gs[0], bs[0], A);
        k_convpoolmf<4, 11, 1, 1, 8, 1, 6, 224, 224>
            <<<dim3(36, 64), TPB, 0, stream>>>(A, wfrag + foff[0], P);
    }
    // ================= L1 =================
    {
        long long Pcnt = 64ll * 212 * 212;
        k_statsN<8><<<dim3(NBX, 1), TPB, 0, stream>>>(P, Pcnt, partial, NBX);
        k_finalize<<<1, 64, 0, stream>>>(partial, mr + 128, 8, (double)Pcnt, NBX);
        k_bnsignN<8><<<dim3(cdiv(Pcnt, TPB), 1), TPB, 0, stream>>>(P, mr + 128, gs[1], bs[1], A, Pcnt);
        k_convpoolmf<8, 7, 1, 1, 16, 2, 2, 212, 212>
            <<<dim3(51, 64), TPB, 0, stream>>>(A, wfrag + foff[1], P);
    }
    // ================= L2 =================
    {
        long long Pcnt = 64ll * 102 * 102;
        k_statsN<16><<<dim3(NBX, 2), TPB, 0, stream>>>(P, Pcnt, partial, NBX);
        k_finalize<<<1, 64, 0, stream>>>(partial, mr + 256, 16, (double)Pcnt, NBX);
        k_bnsignN<16><<<dim3(cdiv(Pcnt, TPB), 2), TPB, 0, stream>>>(P, mr + 256, gs[2], bs[2], A, Pcnt);
        k_convpoolmf<16, 5, 2, 2, 32, 2, 2, 102, 102>
            <<<dim3(24, 64), TPB, 0, stream>>>(A, wfrag + foff[2], P);
    }
    // ================= L3 =================
    {
        long long Pcnt = 64ll * 48 * 48;
        k_statsN<32><<<dim3(NBX, 4), TPB, 0, stream>>>(P, Pcnt, partial, NBX);
        k_finalize<<<1, 64, 0, stream>>>(partial, mr + 384, 32, (double)Pcnt, NBX);
        k_bnsignN<32><<<dim3(cdiv(Pcnt, TPB), 4), TPB, 0, stream>>>(P, mr + 384, gs[3], bs[3], A, Pcnt);
        k_convpoolmf<32, 5, 3, 2, 32, 2, 3, 48, 48>
            <<<dim3(7, 64), TPB, 0, stream>>>(A, wfrag + foff[3], P);
    }
    // ================= L4 =================
    {
        long long Pcnt = 64ll * 21 * 21;
        k_statsN<32><<<dim3(NBX, 4), TPB, 0, stream>>>(P, Pcnt, partial, NBX);
        k_finalize<<<1, 64, 0, stream>>>(partial, mr + 512, 32, (double)Pcnt, NBX);
        k_bnsignN<32><<<dim3(cdiv(Pcnt, TPB), 4), TPB, 0, stream>>>(P, mr + 512, gs[4], bs[4], A, Pcnt);
        k_convpoolmf<32, 5, 3, 4, 64, 2, 2, 21, 21>
            <<<dim3(4, 64), TPB, 0, stream>>>(A, wfrag + foff[4], P);
    }
    // ================= L5 =================
    {
        long long Pcnt = 64ll * 8 * 8;
        k_statsN<64><<<dim3(NBX, 8), TPB, 0, stream>>>(P, Pcnt, partial, NBX);
        k_finalize<<<1, 64, 0, stream>>>(partial, mr + 640, 64, (double)Pcnt, NBX);
        k_bnsignN<64><<<dim3(cdiv(Pcnt, TPB), 8), TPB, 0, stream>>>(P, mr + 640, gs[5], bs[5], A, Pcnt);
        k_convpoolmf<64, 3, 3, 4, 64, 2, 1, 8, 8>
            <<<dim3(2, 64), TPB, 0, stream>>>(A, wfrag + foff[5], P);
    }
    // ================= L6: bn -> sign; FC =================
    {
        long long Pcnt = 64ll * 2 * 2;
        k_statsN<64><<<dim3(NBX, 8), TPB, 0, stream>>>(P, Pcnt, partial, NBX);
        k_finalize<<<1, 64, 0, stream>>>(partial, mr + 768, 64, (double)Pcnt, NBX);
        k_bnsignN<64><<<dim3(cdiv(Pcnt, TPB), 8), TPB, 0, stream>>>(P, mr + 768, gs[6], bs[6], A, Pcnt);
        k_fc<<<dim3(cdiv(64 * 50, TPB)), TPB, 0, stream>>>(A, wbfc, (float*)d_out);
    }
}